// Round 14
// baseline (227.376 us; speedup 1.0000x reference)
//
#include <hip/hip_runtime.h>
#include <math.h>

#define NHID 128
#define CHUNK 1024

typedef __attribute__((ext_vector_type(8))) short bf16x8;
typedef __attribute__((ext_vector_type(4))) float f32x4;

union BF8 { ushort u[8]; bf16x8 v; };

__device__ __forceinline__ ushort f2bf(float f) {
    unsigned int u = __float_as_uint(f);
    u += 0x7FFFu + ((u >> 16) & 1u);      // round-to-nearest-even
    return (ushort)(u >> 16);
}
__device__ __forceinline__ float bfh(unsigned int v) { return __uint_as_float(v << 16); }
__device__ __forceinline__ float bfl(unsigned int v) { return __uint_as_float(v & 0xffff0000u); }

// Branch-free GELU (A&S 7.1.26 erf, max err ~1.5e-7) — scalar, known-good.
// (pk-asm gelu failed twice; LDS-table gelu measured SLOWER (83 vs 62 us, r12).)
__device__ __forceinline__ float gelu_fast(float x) {
    float ax = fabsf(x);
    float t  = __builtin_amdgcn_rcpf(fmaf(0.23165493f, ax, 1.0f));
    float p  = t * fmaf(t, fmaf(t, fmaf(t, fmaf(t, 1.061405429f, -1.453152027f),
                                        1.421413741f), -0.284496736f), 0.254829592f);
    float e  = __builtin_amdgcn_exp2f(-0.7213475204f * ax * ax);
    float hax = 0.5f * ax;
    return fmaf(-hax, p * e, 0.5f * x + hax);
}

// ---------------------------------------------------------------------------
// Fused weight prep + edge histogram.  Fragment-major weights: element (c,k)
// of [C][K] -> ((c/16)*KK + k/32)*512 + (c%16)*32 + (k%32).
//   blocks 0-319   : WC1F   blocks 320-447 : WUCF + BV
//   blocks 448-511 : WU2F   blocks 512+    : histogram of dst into DEG
// ---------------------------------------------------------------------------
__global__ __launch_bounds__(256) void k_prep(
    const float* __restrict__ Wm1, const float* __restrict__ Wu1,
    const float* __restrict__ Wm2, const float* __restrict__ bm2,
    const float* __restrict__ Wu2, const int* __restrict__ dstI, int E,
    ushort* __restrict__ WC1F, ushort* __restrict__ WUCF,
    ushort* __restrict__ WU2F, float* __restrict__ BV, int* __restrict__ deg)
{
    int bid = blockIdx.x, tid = threadIdx.x;
    if (bid < 320) {                      // WC1F
        int idx = bid * 256 + tid;
        int c = idx / 320, k = idx % 320;
        float v;
        if (k < 128) {
            v = (c < 128) ? Wm1[k * 128 + c] : Wm1[(128 + k) * 128 + (c - 128)];
        } else if (k < 256) {
            int kk = k - 128;
            v = (c < 128) ? Wm1[(256 + kk) * 128 + c] : -Wm1[(256 + kk) * 128 + (c - 128)];
        } else {
            int kk = k - 256;
            v = (c < 128) ? 0.0f : Wm1[(384 + kk) * 128 + (c - 128)];
        }
        int dst = ((c >> 4) * 10 + (k >> 5)) * 512 + ((c & 15) << 5) + (k & 31);
        WC1F[dst] = f2bf(v);
    } else if (bid < 448) {               // WUCF + BV
        int idx = (bid - 320) * 256 + tid;
        int c = idx >> 8, k = idx & 255;
        float v;
        if (k < 128) {
            v = Wu1[k * 128 + c];
        } else {
            int i = k - 128;
            float acc = 0.f;
            for (int j = 0; j < 128; ++j) acc += Wm2[i * 128 + j] * Wu1[(128 + j) * 128 + c];
            v = acc;
        }
        int dst = ((c >> 4) * 8 + (k >> 5)) * 512 + ((c & 15) << 5) + (k & 31);
        WUCF[dst] = f2bf(v);
        if (idx < 128) {
            float acc = 0.f;
            for (int j = 0; j < 128; ++j) acc += bm2[j] * Wu1[(128 + j) * 128 + idx];
            BV[idx] = acc;
        }
    } else if (bid < 512) {               // WU2F
        int idx = (bid - 448) * 256 + tid;
        int c = idx >> 7, k = idx & 127;
        int dst = ((c >> 4) * 4 + (k >> 5)) * 512 + ((c & 15) << 5) + (k & 31);
        WU2F[dst] = f2bf(Wu2[k * 128 + c]);
    } else {                              // histogram
        int i = (bid - 512) * 256 + tid;
        if (i < E) atomicAdd(&deg[dstI[i]], 1);
    }
}

// ---------------------------------------------------------------------------
// Counting sort tail: chunksum -> chunkscan -> chunkoffs -> scatter
// ---------------------------------------------------------------------------
__global__ __launch_bounds__(256) void k_chunksum(const int* __restrict__ deg,
                                                  int* __restrict__ csum) {
    int c = blockIdx.x, tid = threadIdx.x;
    int4 v = ((const int4*)(deg + (size_t)c * CHUNK))[tid];
    int ts = v.x + v.y + v.z + v.w;
    #pragma unroll
    for (int d = 1; d < 64; d <<= 1) ts += __shfl_xor(ts, d);
    __shared__ int wsum[4];
    if ((tid & 63) == 0) wsum[tid >> 6] = ts;
    __syncthreads();
    if (tid == 0) csum[c] = wsum[0] + wsum[1] + wsum[2] + wsum[3];
}
__global__ void k_chunkscan(const int* __restrict__ csum, int* __restrict__ cbase,
                            int C, int* __restrict__ offs, int N, int E) {
    int lane = threadIdx.x;   // 64
    int carry = 0;
    for (int b = 0; b < C; b += 64) {
        int v = (b + lane < C) ? csum[b + lane] : 0;
        int incl = v;
        #pragma unroll
        for (int d = 1; d < 64; d <<= 1) {
            int t = __shfl_up(incl, d);
            if (lane >= d) incl += t;
        }
        if (b + lane < C) cbase[b + lane] = carry + incl - v;
        carry += __shfl(incl, 63);
    }
    if (lane == 0) offs[N] = E;
}
__global__ __launch_bounds__(256) void k_chunkoffs(const int* __restrict__ deg,
                                                   const int* __restrict__ cbase,
                                                   int* __restrict__ offs,
                                                   int* __restrict__ cursor) {
    int c = blockIdx.x, tid = threadIdx.x;
    int lane = tid & 63, wid = tid >> 6;
    int4 v = ((const int4*)(deg + (size_t)c * CHUNK))[tid];
    int t0 = v.x, t1 = t0 + v.y, t2 = t1 + v.z, ts = t2 + v.w;
    int incl = ts;
    #pragma unroll
    for (int d = 1; d < 64; d <<= 1) {
        int t = __shfl_up(incl, d);
        if (lane >= d) incl += t;
    }
    __shared__ int wz[4];
    if (lane == 63) wz[wid] = incl;
    __syncthreads();
    int wbase = 0;
    for (int k2 = 0; k2 < wid; ++k2) wbase += wz[k2];
    int eb = cbase[c] + wbase + incl - ts;
    int4 o = make_int4(eb, eb + t0, eb + t1, eb + t2);
    ((int4*)(offs + (size_t)c * CHUNK))[tid] = o;
    ((int4*)(cursor + (size_t)c * CHUNK))[tid] = o;
}
__global__ void k_scatter(const int* __restrict__ src, const int* __restrict__ dst,
                          const float* __restrict__ w, int* __restrict__ cursor,
                          int2* __restrict__ rec, int E) {
    int i = blockIdx.x * blockDim.x + threadIdx.x;
    if (i < E) {
        int d = dst[i];
        int pos = atomicAdd(&cursor[d], 1);
        rec[pos] = make_int2(src[i], __float_as_int(w[i]));
    }
}

// ---------------------------------------------------------------------------
// K1 (MFMA): [P|Q] = [s|x|t] @ Wc1.  32-row blocks, A staged once, B frags
// 1024B coalesced loads from fragment-major WC1F (L2-resident), one-ahead
// register prefetch.  NOT fused with scatter (r11: L2 pollution, +35us).
// ---------------------------------------------------------------------------
__global__ __launch_bounds__(256) void k1_mfma(
    const float* __restrict__ s, const float* __restrict__ x, const float* __restrict__ t,
    const ushort* __restrict__ WC1F, const float* __restrict__ bm1,
    ushort* __restrict__ Pb, ushort* __restrict__ Qb, int N)
{
    __shared__ __align__(16) short Asub[32 * 328];
    int tid = threadIdx.x;
    int w = tid >> 6, l = tid & 63;
    int lr = l & 15, lkq = l >> 4;
    int lk = lkq * 8;
    int boff = (lr << 5) + (lkq << 3);
    int n0 = blockIdx.x * 32;

    {
        int ar = tid & 31;
        int kg = (tid >> 5) * 8;
        int arow = n0 + ar; if (arow >= N) arow = N - 1;
        #pragma unroll
        for (int c = 0; c < 5; ++c) {
            int k = c * 64 + kg;
            const float* asrc;
            if (k < 128)      asrc = s + (size_t)arow * 128 + k;
            else if (k < 256) asrc = x + (size_t)arow * 128 + (k - 128);
            else              asrc = t + (size_t)arow * 64 + (k - 256);
            float4 f0 = *(const float4*)asrc;
            float4 f1 = *(const float4*)(asrc + 4);
            BF8 pk;
            pk.u[0] = f2bf(f0.x); pk.u[1] = f2bf(f0.y); pk.u[2] = f2bf(f0.z); pk.u[3] = f2bf(f0.w);
            pk.u[4] = f2bf(f1.x); pk.u[5] = f2bf(f1.y); pk.u[6] = f2bf(f1.z); pk.u[7] = f2bf(f1.w);
            *(bf16x8*)&Asub[ar * 328 + k] = pk.v;
        }
    }
    __syncthreads();

    f32x4 acc[2][4];
    #pragma unroll
    for (int i = 0; i < 2; ++i)
        #pragma unroll
        for (int j = 0; j < 4; ++j) acc[i][j] = (f32x4){0.f, 0.f, 0.f, 0.f};

    const ushort* wbase = WC1F + boff;
    bf16x8 bcur[4], a0c, a1c;
    #pragma unroll
    for (int ct = 0; ct < 4; ++ct)
        bcur[ct] = *(const bf16x8*)(wbase + (size_t)((w * 4 + ct) * 10) * 512);
    a0c = *(const bf16x8*)&Asub[lr * 328 + lk];
    a1c = *(const bf16x8*)&Asub[(16 + lr) * 328 + lk];

    #pragma unroll
    for (int kk = 0; kk < 10; ++kk) {
        bf16x8 bn[4], a0n, a1n;
        if (kk < 9) {
            #pragma unroll
            for (int ct = 0; ct < 4; ++ct)
                bn[ct] = *(const bf16x8*)(wbase + (size_t)((w * 4 + ct) * 10 + kk + 1) * 512);
            a0n = *(const bf16x8*)&Asub[lr * 328 + (kk + 1) * 32 + lk];
            a1n = *(const bf16x8*)&Asub[(16 + lr) * 328 + (kk + 1) * 32 + lk];
        }
        #pragma unroll
        for (int ct = 0; ct < 4; ++ct) {
            acc[0][ct] = __builtin_amdgcn_mfma_f32_16x16x32_bf16(a0c, bcur[ct], acc[0][ct], 0, 0, 0);
            acc[1][ct] = __builtin_amdgcn_mfma_f32_16x16x32_bf16(a1c, bcur[ct], acc[1][ct], 0, 0, 0);
        }
        if (kk < 9) {
            #pragma unroll
            for (int ct = 0; ct < 4; ++ct) bcur[ct] = bn[ct];
            a0c = a0n; a1c = a1n;
        }
    }

    int rbase = lkq * 4;
    #pragma unroll
    for (int ct = 0; ct < 4; ++ct) {
        int col = w * 64 + ct * 16 + lr;
        float bb = (col >= 128) ? bm1[col - 128] : 0.f;
        #pragma unroll
        for (int rt = 0; rt < 2; ++rt) {
            #pragma unroll
            for (int r = 0; r < 4; ++r) {
                int row = n0 + rt * 16 + rbase + r;
                if (row < N) {
                    float v = acc[rt][ct][r];
                    if (col < 128) Pb[(size_t)row * 128 + col] = f2bf(v);
                    else           Qb[(size_t)row * 128 + (col - 128)] = f2bf(v + bb);
                }
            }
        }
    }
}

// ---------------------------------------------------------------------------
// K_AGG3 (fused aggregation + update MLP).  Block = 32 nodes; wave w handles
// nodes n0+w*8..+7 sequentially with the known-good segmented-reduction loop,
// writing bf16 agg DIRECTLY into the k3 A-tile in LDS (cols 128..255) and sw
// into LDS.  Then one barrier and the k3 MFMA phases run in place.
// Eliminates GAB round-trip (25.6MB), the k3 launch, and half of A staging.
// ---------------------------------------------------------------------------
__global__ __launch_bounds__(256) void k_agg3(
    const ushort* __restrict__ Pb, const ushort* __restrict__ Qb,
    const int2* __restrict__ rec, const int* __restrict__ offs,
    const float* __restrict__ s,
    const ushort* __restrict__ WUCF, const float* __restrict__ BV,
    const float* __restrict__ bu1,
    const ushort* __restrict__ WU2F, const float* __restrict__ bu2,
    float* __restrict__ out, int N)
{
    __shared__ __align__(16) short Asub[32 * 264];   // [row][k]: k<128 = s, k>=128 = agg
    __shared__ __align__(16) short H2[32 * 136];
    __shared__ float SWs[32];
    int tid = threadIdx.x;
    int w = tid >> 6, l = tid & 63;
    int n0 = blockIdx.x * 32;
    unsigned lo2 = (unsigned)(l << 1);

    // ---- Phase 1: segmented aggregation, 8 nodes per wave
    for (int i = 0; i < 8; ++i) {
        int n = n0 + w * 8 + i;
        if (n >= N) break;
        int local = w * 8 + i;
        int beg = __builtin_amdgcn_readfirstlane(offs[n]);
        int end = __builtin_amdgcn_readfirstlane(offs[n + 1]);
        unsigned int qv = *(const unsigned int*)&Qb[((unsigned)n << 7) + lo2];
        float qx = bfh(qv), qy = bfl(qv);
        float a0 = 0.f, a1 = 0.f, wsum = 0.f;
        int j = beg;
        if (j + 4 <= end) {
            int2 r0 = rec[j], r1 = rec[j + 1], r2 = rec[j + 2], r3 = rec[j + 3];
            unsigned int p0 = *(const unsigned int*)&Pb[((unsigned)r0.x << 7) + lo2];
            unsigned int p1 = *(const unsigned int*)&Pb[((unsigned)r1.x << 7) + lo2];
            unsigned int p2 = *(const unsigned int*)&Pb[((unsigned)r2.x << 7) + lo2];
            unsigned int p3 = *(const unsigned int*)&Pb[((unsigned)r3.x << 7) + lo2];
            j += 4;
            while (j + 4 <= end) {
                int2 s0 = rec[j], s1 = rec[j + 1], s2 = rec[j + 2], s3 = rec[j + 3];
                unsigned int n0_ = *(const unsigned int*)&Pb[((unsigned)s0.x << 7) + lo2];
                unsigned int n1_ = *(const unsigned int*)&Pb[((unsigned)s1.x << 7) + lo2];
                unsigned int n2_ = *(const unsigned int*)&Pb[((unsigned)s2.x << 7) + lo2];
                unsigned int n3_ = *(const unsigned int*)&Pb[((unsigned)s3.x << 7) + lo2];
                float w0 = __int_as_float(r0.y), w1 = __int_as_float(r1.y);
                float w2 = __int_as_float(r2.y), w3 = __int_as_float(r3.y);
                a0 = fmaf(w0, gelu_fast(bfh(p0) + qx), a0);
                a1 = fmaf(w0, gelu_fast(bfl(p0) + qy), a1);
                a0 = fmaf(w1, gelu_fast(bfh(p1) + qx), a0);
                a1 = fmaf(w1, gelu_fast(bfl(p1) + qy), a1);
                a0 = fmaf(w2, gelu_fast(bfh(p2) + qx), a0);
                a1 = fmaf(w2, gelu_fast(bfl(p2) + qy), a1);
                a0 = fmaf(w3, gelu_fast(bfh(p3) + qx), a0);
                a1 = fmaf(w3, gelu_fast(bfl(p3) + qy), a1);
                wsum += (w0 + w1) + (w2 + w3);
                r0 = s0; r1 = s1; r2 = s2; r3 = s3;
                p0 = n0_; p1 = n1_; p2 = n2_; p3 = n3_;
                j += 4;
            }
            float w0 = __int_as_float(r0.y), w1 = __int_as_float(r1.y);
            float w2 = __int_as_float(r2.y), w3 = __int_as_float(r3.y);
            a0 = fmaf(w0, gelu_fast(bfh(p0) + qx), a0);
            a1 = fmaf(w0, gelu_fast(bfl(p0) + qy), a1);
            a0 = fmaf(w1, gelu_fast(bfh(p1) + qx), a0);
            a1 = fmaf(w1, gelu_fast(bfl(p1) + qy), a1);
            a0 = fmaf(w2, gelu_fast(bfh(p2) + qx), a0);
            a1 = fmaf(w2, gelu_fast(bfl(p2) + qy), a1);
            a0 = fmaf(w3, gelu_fast(bfh(p3) + qx), a0);
            a1 = fmaf(w3, gelu_fast(bfl(p3) + qy), a1);
            wsum += (w0 + w1) + (w2 + w3);
        }
        for (; j < end; ++j) {
            int2 r0 = rec[j];
            unsigned int p0 = *(const unsigned int*)&Pb[((unsigned)r0.x << 7) + lo2];
            float w0 = __int_as_float(r0.y);
            a0 = fmaf(w0, gelu_fast(bfh(p0) + qx), a0);
            a1 = fmaf(w0, gelu_fast(bfl(p0) + qy), a1);
            wsum += w0;
        }
        *(ushort2*)&Asub[local * 264 + 128 + (l << 1)] = make_ushort2(f2bf(a0), f2bf(a1));
        if (l == 0) SWs[local] = wsum;
    }

    // ---- stage s-half of A-tile (k < 128)
    {
        int ar = tid & 31;
        int kg = (tid >> 5) * 8;
        int arow = n0 + ar; if (arow >= N) arow = N - 1;
        #pragma unroll
        for (int c = 0; c < 2; ++c) {
            int k = c * 64 + kg;
            const float* asrc = s + (size_t)arow * 128 + k;
            float4 f0 = *(const float4*)asrc;
            float4 f1 = *(const float4*)(asrc + 4);
            BF8 pk;
            pk.u[0] = f2bf(f0.x); pk.u[1] = f2bf(f0.y); pk.u[2] = f2bf(f0.z); pk.u[3] = f2bf(f0.w);
            pk.u[4] = f2bf(f1.x); pk.u[5] = f2bf(f1.y); pk.u[6] = f2bf(f1.z); pk.u[7] = f2bf(f1.w);
            *(bf16x8*)&Asub[ar * 264 + k] = pk.v;
        }
    }
    __syncthreads();

    // ---- Phase A: pre2 = [s|agg] @ Wuc (K=256), prefetched
    int lr = l & 15, lkq = l >> 4;
    int lk = lkq * 8;
    int boff = (lr << 5) + (lkq << 3);

    f32x4 acc[2][2];
    #pragma unroll
    for (int i = 0; i < 2; ++i) { acc[i][0] = (f32x4){0,0,0,0}; acc[i][1] = (f32x4){0,0,0,0}; }

    bf16x8 bcur[2], a0c, a1c;
    #pragma unroll
    for (int ct = 0; ct < 2; ++ct)
        bcur[ct] = *(const bf16x8*)(WUCF + (size_t)((w * 2 + ct) * 8) * 512 + boff);
    a0c = *(const bf16x8*)&Asub[lr * 264 + lk];
    a1c = *(const bf16x8*)&Asub[(16 + lr) * 264 + lk];

    #pragma unroll
    for (int kk = 0; kk < 8; ++kk) {
        bf16x8 bn[2], a0n, a1n;
        if (kk < 7) {
            #pragma unroll
            for (int ct = 0; ct < 2; ++ct)
                bn[ct] = *(const bf16x8*)(WUCF + (size_t)((w * 2 + ct) * 8 + kk + 1) * 512 + boff);
            a0n = *(const bf16x8*)&Asub[lr * 264 + (kk + 1) * 32 + lk];
            a1n = *(const bf16x8*)&Asub[(16 + lr) * 264 + (kk + 1) * 32 + lk];
        }
        #pragma unroll
        for (int ct = 0; ct < 2; ++ct) {
            acc[0][ct] = __builtin_amdgcn_mfma_f32_16x16x32_bf16(a0c, bcur[ct], acc[0][ct], 0, 0, 0);
            acc[1][ct] = __builtin_amdgcn_mfma_f32_16x16x32_bf16(a1c, bcur[ct], acc[1][ct], 0, 0, 0);
        }
        if (kk < 7) {
            bcur[0] = bn[0]; bcur[1] = bn[1];
            a0c = a0n; a1c = a1n;
        }
    }

    int rbase = lkq * 4;
    #pragma unroll
    for (int ct = 0; ct < 2; ++ct) {
        int col = w * 32 + ct * 16 + lr;
        float b1 = bu1[col], bv = BV[col];
        #pragma unroll
        for (int rt = 0; rt < 2; ++rt) {
            #pragma unroll
            for (int r = 0; r < 4; ++r) {
                int row16 = rt * 16 + rbase + r;
                float v = acc[rt][ct][r] + b1 + SWs[row16] * bv;
                H2[row16 * 136 + col] = (short)f2bf(gelu_fast(v));
            }
        }
    }
    __syncthreads();

    // ---- Phase B: out = h2 @ Wu2 (K=128), prefetched
    f32x4 acc2[2][2];
    #pragma unroll
    for (int i = 0; i < 2; ++i) { acc2[i][0] = (f32x4){0,0,0,0}; acc2[i][1] = (f32x4){0,0,0,0}; }

    bf16x8 b2c[2], h0c, h1c;
    #pragma unroll
    for (int ct = 0; ct < 2; ++ct)
        b2c[ct] = *(const bf16x8*)(WU2F + (size_t)((w * 2 + ct) * 4) * 512 + boff);
    h0c = *(const bf16x8*)&H2[lr * 136 + lk];
    h1c = *(const bf16x8*)&H2[(16 + lr) * 136 + lk];

    #pragma unroll
    for (int kk = 0; kk < 4; ++kk) {
        bf16x8 bn[2], h0n, h1n;
        if (kk < 3) {
            #pragma unroll
            for (int ct = 0; ct < 2; ++ct)
                bn[ct] = *(const bf16x8*)(WU2F + (size_t)((w * 2 + ct) * 4 + kk + 1) * 512 + boff);
            h0n = *(const bf16x8*)&H2[lr * 136 + (kk + 1) * 32 + lk];
            h1n = *(const bf16x8*)&H2[(16 + lr) * 136 + (kk + 1) * 32 + lk];
        }
        #pragma unroll
        for (int ct = 0; ct < 2; ++ct) {
            acc2[0][ct] = __builtin_amdgcn_mfma_f32_16x16x32_bf16(h0c, b2c[ct], acc2[0][ct], 0, 0, 0);
            acc2[1][ct] = __builtin_amdgcn_mfma_f32_16x16x32_bf16(h1c, b2c[ct], acc2[1][ct], 0, 0, 0);
        }
        if (kk < 3) {
            b2c[0] = bn[0]; b2c[1] = bn[1];
            h0c = h0n; h1c = h1n;
        }
    }

    #pragma unroll
    for (int ct = 0; ct < 2; ++ct) {
        int col = w * 32 + ct * 16 + lr;
        float b2 = bu2[col];
        #pragma unroll
        for (int rt = 0; rt < 2; ++rt) {
            #pragma unroll
            for (int r = 0; r < 4; ++r) {
                int row = n0 + rt * 16 + rbase + r;
                if (row < N) out[(size_t)row * 128 + col] = acc2[rt][ct][r] + b2;
            }
        }
    }
}

// ---------------------------------------------------------------------------
extern "C" void kernel_launch(void* const* d_in, const int* in_sizes, int n_in,
                              void* d_out, int out_size, void* d_ws, size_t ws_size,
                              hipStream_t stream) {
    const float* s    = (const float*)d_in[0];
    const float* x    = (const float*)d_in[1];
    const int*   ei   = (const int*)d_in[2];
    const float* ew   = (const float*)d_in[3];
    const float* t    = (const float*)d_in[4];
    const float* Wm1  = (const float*)d_in[5];
    const float* bm1  = (const float*)d_in[6];
    const float* Wm2  = (const float*)d_in[7];
    const float* bm2  = (const float*)d_in[8];
    const float* Wu1  = (const float*)d_in[9];
    const float* bu1  = (const float*)d_in[10];
    const float* Wu2  = (const float*)d_in[11];
    const float* bu2  = (const float*)d_in[12];

    int N = in_sizes[0] / 128;
    int E = in_sizes[2] / 2;
    const int* srcI = ei;
    const int* dstI = ei + E;
    int NP = (N + CHUNK - 1) & ~(CHUNK - 1);
    int C  = NP / CHUNK;

    // workspace layout (32-bit words)
    float* ws = (float*)d_ws;
    size_t off = 0;
    ushort* Pb   = (ushort*)(ws + off); off += (size_t)N * 64;
    ushort* Qb   = (ushort*)(ws + off); off += (size_t)N * 64;
    ushort* WC1F = (ushort*)(ws + off); off += (256 * 320) / 2;
    ushort* WUCF = (ushort*)(ws + off); off += (128 * 256) / 2;
    ushort* WU2F = (ushort*)(ws + off); off += (128 * 128) / 2;
    float*  BV   = ws + off; off += 128;
    int*    DEG  = (int*)(ws + off); off += (size_t)NP;
    int*    OFFS = (int*)(ws + off); off += (size_t)NP + 64;
    off = (off + 3) & ~(size_t)3;
    int*    CUR  = (int*)(ws + off); off += (size_t)NP;
    int*    CSUM = (int*)(ws + off); off += 128;
    int*    CBASE= (int*)(ws + off); off += 128;
    off = (off + 3) & ~(size_t)3;
    int2*   REC  = (int2*)(ws + off); off += (size_t)E * 2;

    // zero histogram, then fused weight-prep + histogram
    hipMemsetAsync(DEG, 0, (size_t)NP * sizeof(int), stream);
    int histBlocks = (E + 255) / 256;
    k_prep<<<512 + histBlocks, 256, 0, stream>>>(Wm1, Wu1, Wm2, bm2, Wu2, dstI, E,
                                                 WC1F, WUCF, WU2F, BV, DEG);

    // counting sort tail
    k_chunksum<<<C, 256, 0, stream>>>(DEG, CSUM);
    k_chunkscan<<<1, 64, 0, stream>>>(CSUM, CBASE, C, OFFS, N, E);
    k_chunkoffs<<<C, 256, 0, stream>>>(DEG, CBASE, OFFS, CUR);
    k_scatter<<<(E + 255) / 256, 256, 0, stream>>>(srcI, dstI, ew, CUR, REC, E);

    // node precompute (MFMA)
    int nb32 = (N + 31) / 32;
    k1_mfma<<<nb32, 256, 0, stream>>>(s, x, t, WC1F, bm1, Pb, Qb, N);

    // fused aggregation + update MLP
    k_agg3<<<nb32, 256, 0, stream>>>(Pb, Qb, REC, OFFS, s, WUCF, BV, bu1,
                                     WU2F, bu2, (float*)d_out, N);
}

// Round 15
// 223.109 us; speedup vs baseline: 1.0191x; 1.0191x over previous
//
#include <hip/hip_runtime.h>
#include <math.h>

#define NHID 128
#define CHUNK 1024

typedef __attribute__((ext_vector_type(8))) short bf16x8;
typedef __attribute__((ext_vector_type(4))) float f32x4;
typedef __attribute__((ext_vector_type(2))) float f32x2;

union BF8 { ushort u[8]; bf16x8 v; };

__device__ __forceinline__ ushort f2bf(float f) {
    unsigned int u = __float_as_uint(f);
    u += 0x7FFFu + ((u >> 16) & 1u);      // round-to-nearest-even
    return (ushort)(u >> 16);
}
__device__ __forceinline__ float bfh(unsigned int v) { return __uint_as_float(v << 16); }
__device__ __forceinline__ float bfl(unsigned int v) { return __uint_as_float(v & 0xffff0000u); }

// Branch-free GELU (A&S 7.1.26 erf, max err ~1.5e-7) — scalar, known-good.
// (hand-asm v_pk gelu failed twice (VOP3P op_sel semantics); LDS-table gelu
//  measured SLOWER (83 vs 62 us, r12). k3 epilogue uses this scalar form.)
__device__ __forceinline__ float gelu_fast(float x) {
    float ax = fabsf(x);
    float t  = __builtin_amdgcn_rcpf(fmaf(0.23165493f, ax, 1.0f));
    float p  = t * fmaf(t, fmaf(t, fmaf(t, fmaf(t, 1.061405429f, -1.453152027f),
                                        1.421413741f), -0.284496736f), 0.254829592f);
    float e  = __builtin_amdgcn_exp2f(-0.7213475204f * ax * ax);
    float hax = 0.5f * ax;
    return fmaf(-hax, p * e, 0.5f * x + hax);
}

// Vector (float2) GELU — pure C vector ops, NO inline asm. Per-lane math is
// operation-identical to gelu_fast; backend may select v_pk_fma_f32/v_pk_mul_f32
// (gfx90a+ packed fp32) from the <2 x float> IR. Worst case: scalarizes (neutral).
__device__ __forceinline__ f32x2 gelu2v(f32x2 x) {
    f32x2 ax = { fabsf(x.x), fabsf(x.y) };
    f32x2 t  = { __builtin_amdgcn_rcpf(fmaf(0.23165493f, ax.x, 1.0f)),
                 __builtin_amdgcn_rcpf(fmaf(0.23165493f, ax.y, 1.0f)) };
    f32x2 p;
    p = __builtin_elementwise_fma(t, (f32x2){1.061405429f, 1.061405429f},
                                  (f32x2){-1.453152027f, -1.453152027f});
    p = __builtin_elementwise_fma(t, p, (f32x2){1.421413741f, 1.421413741f});
    p = __builtin_elementwise_fma(t, p, (f32x2){-0.284496736f, -0.284496736f});
    p = __builtin_elementwise_fma(t, p, (f32x2){0.254829592f, 0.254829592f});
    p = p * t;
    f32x2 ax2 = ax * ax;
    f32x2 e = { __builtin_amdgcn_exp2f(-0.7213475204f * ax2.x),
                __builtin_amdgcn_exp2f(-0.7213475204f * ax2.y) };
    f32x2 pe   = p * e;
    f32x2 hax  = ax * (f32x2){0.5f, 0.5f};
    f32x2 nhax = ax * (f32x2){-0.5f, -0.5f};
    f32x2 base = __builtin_elementwise_fma(x, (f32x2){0.5f, 0.5f}, hax);
    return __builtin_elementwise_fma(nhax, pe, base);
}

// ---------------------------------------------------------------------------
// Fused weight prep + edge histogram.  Fragment-major weights: element (c,k)
// of [C][K] -> ((c/16)*KK + k/32)*512 + (c%16)*32 + (k%32).
//   blocks 0-319   : WC1F   blocks 320-447 : WUCF + BV
//   blocks 448-511 : WU2F   blocks 512+    : histogram of dst into DEG
// ---------------------------------------------------------------------------
__global__ __launch_bounds__(256) void k_prep(
    const float* __restrict__ Wm1, const float* __restrict__ Wu1,
    const float* __restrict__ Wm2, const float* __restrict__ bm2,
    const float* __restrict__ Wu2, const int* __restrict__ dstI, int E,
    ushort* __restrict__ WC1F, ushort* __restrict__ WUCF,
    ushort* __restrict__ WU2F, float* __restrict__ BV, int* __restrict__ deg)
{
    int bid = blockIdx.x, tid = threadIdx.x;
    if (bid < 320) {                      // WC1F
        int idx = bid * 256 + tid;
        int c = idx / 320, k = idx % 320;
        float v;
        if (k < 128) {
            v = (c < 128) ? Wm1[k * 128 + c] : Wm1[(128 + k) * 128 + (c - 128)];
        } else if (k < 256) {
            int kk = k - 128;
            v = (c < 128) ? Wm1[(256 + kk) * 128 + c] : -Wm1[(256 + kk) * 128 + (c - 128)];
        } else {
            int kk = k - 256;
            v = (c < 128) ? 0.0f : Wm1[(384 + kk) * 128 + (c - 128)];
        }
        int dst = ((c >> 4) * 10 + (k >> 5)) * 512 + ((c & 15) << 5) + (k & 31);
        WC1F[dst] = f2bf(v);
    } else if (bid < 448) {               // WUCF + BV
        int idx = (bid - 320) * 256 + tid;
        int c = idx >> 8, k = idx & 255;
        float v;
        if (k < 128) {
            v = Wu1[k * 128 + c];
        } else {
            int i = k - 128;
            float acc = 0.f;
            for (int j = 0; j < 128; ++j) acc += Wm2[i * 128 + j] * Wu1[(128 + j) * 128 + c];
            v = acc;
        }
        int dst = ((c >> 4) * 8 + (k >> 5)) * 512 + ((c & 15) << 5) + (k & 31);
        WUCF[dst] = f2bf(v);
        if (idx < 128) {
            float acc = 0.f;
            for (int j = 0; j < 128; ++j) acc += bm2[j] * Wu1[(128 + j) * 128 + idx];
            BV[idx] = acc;
        }
    } else if (bid < 512) {               // WU2F
        int idx = (bid - 448) * 256 + tid;
        int c = idx >> 7, k = idx & 127;
        int dst = ((c >> 4) * 4 + (k >> 5)) * 512 + ((c & 15) << 5) + (k & 31);
        WU2F[dst] = f2bf(Wu2[k * 128 + c]);
    } else {                              // histogram
        int i = (bid - 512) * 256 + tid;
        if (i < E) atomicAdd(&deg[dstI[i]], 1);
    }
}

// ---------------------------------------------------------------------------
// Counting sort tail: chunksum -> chunkscan -> chunkoffs -> scatter
// ---------------------------------------------------------------------------
__global__ __launch_bounds__(256) void k_chunksum(const int* __restrict__ deg,
                                                  int* __restrict__ csum) {
    int c = blockIdx.x, tid = threadIdx.x;
    int4 v = ((const int4*)(deg + (size_t)c * CHUNK))[tid];
    int ts = v.x + v.y + v.z + v.w;
    #pragma unroll
    for (int d = 1; d < 64; d <<= 1) ts += __shfl_xor(ts, d);
    __shared__ int wsum[4];
    if ((tid & 63) == 0) wsum[tid >> 6] = ts;
    __syncthreads();
    if (tid == 0) csum[c] = wsum[0] + wsum[1] + wsum[2] + wsum[3];
}
__global__ void k_chunkscan(const int* __restrict__ csum, int* __restrict__ cbase,
                            int C, int* __restrict__ offs, int N, int E) {
    int lane = threadIdx.x;   // 64
    int carry = 0;
    for (int b = 0; b < C; b += 64) {
        int v = (b + lane < C) ? csum[b + lane] : 0;
        int incl = v;
        #pragma unroll
        for (int d = 1; d < 64; d <<= 1) {
            int t = __shfl_up(incl, d);
            if (lane >= d) incl += t;
        }
        if (b + lane < C) cbase[b + lane] = carry + incl - v;
        carry += __shfl(incl, 63);
    }
    if (lane == 0) offs[N] = E;
}
__global__ __launch_bounds__(256) void k_chunkoffs(const int* __restrict__ deg,
                                                   const int* __restrict__ cbase,
                                                   int* __restrict__ offs,
                                                   int* __restrict__ cursor) {
    int c = blockIdx.x, tid = threadIdx.x;
    int lane = tid & 63, wid = tid >> 6;
    int4 v = ((const int4*)(deg + (size_t)c * CHUNK))[tid];
    int t0 = v.x, t1 = t0 + v.y, t2 = t1 + v.z, ts = t2 + v.w;
    int incl = ts;
    #pragma unroll
    for (int d = 1; d < 64; d <<= 1) {
        int t = __shfl_up(incl, d);
        if (lane >= d) incl += t;
    }
    __shared__ int wz[4];
    if (lane == 63) wz[wid] = incl;
    __syncthreads();
    int wbase = 0;
    for (int k2 = 0; k2 < wid; ++k2) wbase += wz[k2];
    int eb = cbase[c] + wbase + incl - ts;
    int4 o = make_int4(eb, eb + t0, eb + t1, eb + t2);
    ((int4*)(offs + (size_t)c * CHUNK))[tid] = o;
    ((int4*)(cursor + (size_t)c * CHUNK))[tid] = o;
}
__global__ void k_scatter(const int* __restrict__ src, const int* __restrict__ dst,
                          const float* __restrict__ w, int* __restrict__ cursor,
                          int2* __restrict__ rec, int E) {
    int i = blockIdx.x * blockDim.x + threadIdx.x;
    if (i < E) {
        int d = dst[i];
        int pos = atomicAdd(&cursor[d], 1);
        rec[pos] = make_int2(src[i], __float_as_int(w[i]));
    }
}

// ---------------------------------------------------------------------------
// K1 (MFMA): [P|Q] = [s|x|t] @ Wc1.  32-row blocks, A staged once, B frags
// 1024B coalesced loads from fragment-major WC1F (L2-resident), one-ahead
// register prefetch.  NOT fused with scatter (r11: L2 pollution, +35us).
// NOT fused with agg (r14: occupancy loss on agg phase, net-neutral).
// ---------------------------------------------------------------------------
__global__ __launch_bounds__(256) void k1_mfma(
    const float* __restrict__ s, const float* __restrict__ x, const float* __restrict__ t,
    const ushort* __restrict__ WC1F, const float* __restrict__ bm1,
    ushort* __restrict__ Pb, ushort* __restrict__ Qb, int N)
{
    __shared__ __align__(16) short Asub[32 * 328];
    int tid = threadIdx.x;
    int w = tid >> 6, l = tid & 63;
    int lr = l & 15, lkq = l >> 4;
    int lk = lkq * 8;
    int boff = (lr << 5) + (lkq << 3);
    int n0 = blockIdx.x * 32;

    {
        int ar = tid & 31;
        int kg = (tid >> 5) * 8;
        int arow = n0 + ar; if (arow >= N) arow = N - 1;
        #pragma unroll
        for (int c = 0; c < 5; ++c) {
            int k = c * 64 + kg;
            const float* asrc;
            if (k < 128)      asrc = s + (size_t)arow * 128 + k;
            else if (k < 256) asrc = x + (size_t)arow * 128 + (k - 128);
            else              asrc = t + (size_t)arow * 64 + (k - 256);
            float4 f0 = *(const float4*)asrc;
            float4 f1 = *(const float4*)(asrc + 4);
            BF8 pk;
            pk.u[0] = f2bf(f0.x); pk.u[1] = f2bf(f0.y); pk.u[2] = f2bf(f0.z); pk.u[3] = f2bf(f0.w);
            pk.u[4] = f2bf(f1.x); pk.u[5] = f2bf(f1.y); pk.u[6] = f2bf(f1.z); pk.u[7] = f2bf(f1.w);
            *(bf16x8*)&Asub[ar * 328 + k] = pk.v;
        }
    }
    __syncthreads();

    f32x4 acc[2][4];
    #pragma unroll
    for (int i = 0; i < 2; ++i)
        #pragma unroll
        for (int j = 0; j < 4; ++j) acc[i][j] = (f32x4){0.f, 0.f, 0.f, 0.f};

    const ushort* wbase = WC1F + boff;
    bf16x8 bcur[4], a0c, a1c;
    #pragma unroll
    for (int ct = 0; ct < 4; ++ct)
        bcur[ct] = *(const bf16x8*)(wbase + (size_t)((w * 4 + ct) * 10) * 512);
    a0c = *(const bf16x8*)&Asub[lr * 328 + lk];
    a1c = *(const bf16x8*)&Asub[(16 + lr) * 328 + lk];

    #pragma unroll
    for (int kk = 0; kk < 10; ++kk) {
        bf16x8 bn[4], a0n, a1n;
        if (kk < 9) {
            #pragma unroll
            for (int ct = 0; ct < 4; ++ct)
                bn[ct] = *(const bf16x8*)(wbase + (size_t)((w * 4 + ct) * 10 + kk + 1) * 512);
            a0n = *(const bf16x8*)&Asub[lr * 328 + (kk + 1) * 32 + lk];
            a1n = *(const bf16x8*)&Asub[(16 + lr) * 328 + (kk + 1) * 32 + lk];
        }
        #pragma unroll
        for (int ct = 0; ct < 4; ++ct) {
            acc[0][ct] = __builtin_amdgcn_mfma_f32_16x16x32_bf16(a0c, bcur[ct], acc[0][ct], 0, 0, 0);
            acc[1][ct] = __builtin_amdgcn_mfma_f32_16x16x32_bf16(a1c, bcur[ct], acc[1][ct], 0, 0, 0);
        }
        if (kk < 9) {
            #pragma unroll
            for (int ct = 0; ct < 4; ++ct) bcur[ct] = bn[ct];
            a0c = a0n; a1c = a1n;
        }
    }

    int rbase = lkq * 4;
    #pragma unroll
    for (int ct = 0; ct < 4; ++ct) {
        int col = w * 64 + ct * 16 + lr;
        float bb = (col >= 128) ? bm1[col - 128] : 0.f;
        #pragma unroll
        for (int rt = 0; rt < 2; ++rt) {
            #pragma unroll
            for (int r = 0; r < 4; ++r) {
                int row = n0 + rt * 16 + rbase + r;
                if (row < N) {
                    float v = acc[rt][ct][r];
                    if (col < 128) Pb[(size_t)row * 128 + col] = f2bf(v);
                    else           Qb[(size_t)row * 128 + (col - 128)] = f2bf(v + bb);
                }
            }
        }
    }
}

// ---------------------------------------------------------------------------
// K_agg: segmented reduction, one wave per dst node, 2 ch/lane (f32x2 vector
// math — compiler may select packed v_pk_* fp32).  Software-pipelined gathers.
// ---------------------------------------------------------------------------
__global__ __launch_bounds__(256) void k_agg(
    const ushort* __restrict__ Pb, const ushort* __restrict__ Qb,
    const int2* __restrict__ rec, const int* __restrict__ offs,
    ushort* __restrict__ GAB, float* __restrict__ sw, int N)
{
    int n = blockIdx.x * 4 + (threadIdx.x >> 6);
    if (n >= N) return;
    int lane = threadIdx.x & 63;
    unsigned lo2 = (unsigned)(lane << 1);
    int beg = __builtin_amdgcn_readfirstlane(offs[n]);
    int end = __builtin_amdgcn_readfirstlane(offs[n + 1]);
    unsigned int qv = *(const unsigned int*)&Qb[((unsigned)n << 7) + lo2];
    f32x2 q = { bfh(qv), bfl(qv) };
    f32x2 a = { 0.f, 0.f };
    float wsum = 0.f;
    int j = beg;
    if (j + 4 <= end) {
        int2 r0 = rec[j], r1 = rec[j + 1], r2 = rec[j + 2], r3 = rec[j + 3];
        unsigned int p0 = *(const unsigned int*)&Pb[((unsigned)r0.x << 7) + lo2];
        unsigned int p1 = *(const unsigned int*)&Pb[((unsigned)r1.x << 7) + lo2];
        unsigned int p2 = *(const unsigned int*)&Pb[((unsigned)r2.x << 7) + lo2];
        unsigned int p3 = *(const unsigned int*)&Pb[((unsigned)r3.x << 7) + lo2];
        j += 4;
        while (j + 4 <= end) {
            int2 s0 = rec[j], s1 = rec[j + 1], s2 = rec[j + 2], s3 = rec[j + 3];
            unsigned int n0_ = *(const unsigned int*)&Pb[((unsigned)s0.x << 7) + lo2];
            unsigned int n1_ = *(const unsigned int*)&Pb[((unsigned)s1.x << 7) + lo2];
            unsigned int n2_ = *(const unsigned int*)&Pb[((unsigned)s2.x << 7) + lo2];
            unsigned int n3_ = *(const unsigned int*)&Pb[((unsigned)s3.x << 7) + lo2];
            float w0 = __int_as_float(r0.y), w1 = __int_as_float(r1.y);
            float w2 = __int_as_float(r2.y), w3 = __int_as_float(r3.y);
            a = __builtin_elementwise_fma((f32x2){w0, w0}, gelu2v((f32x2){bfh(p0), bfl(p0)} + q), a);
            a = __builtin_elementwise_fma((f32x2){w1, w1}, gelu2v((f32x2){bfh(p1), bfl(p1)} + q), a);
            a = __builtin_elementwise_fma((f32x2){w2, w2}, gelu2v((f32x2){bfh(p2), bfl(p2)} + q), a);
            a = __builtin_elementwise_fma((f32x2){w3, w3}, gelu2v((f32x2){bfh(p3), bfl(p3)} + q), a);
            wsum += (w0 + w1) + (w2 + w3);
            r0 = s0; r1 = s1; r2 = s2; r3 = s3;
            p0 = n0_; p1 = n1_; p2 = n2_; p3 = n3_;
            j += 4;
        }
        float w0 = __int_as_float(r0.y), w1 = __int_as_float(r1.y);
        float w2 = __int_as_float(r2.y), w3 = __int_as_float(r3.y);
        a = __builtin_elementwise_fma((f32x2){w0, w0}, gelu2v((f32x2){bfh(p0), bfl(p0)} + q), a);
        a = __builtin_elementwise_fma((f32x2){w1, w1}, gelu2v((f32x2){bfh(p1), bfl(p1)} + q), a);
        a = __builtin_elementwise_fma((f32x2){w2, w2}, gelu2v((f32x2){bfh(p2), bfl(p2)} + q), a);
        a = __builtin_elementwise_fma((f32x2){w3, w3}, gelu2v((f32x2){bfh(p3), bfl(p3)} + q), a);
        wsum += (w0 + w1) + (w2 + w3);
    }
    for (; j < end; ++j) {
        int2 r0 = rec[j];
        unsigned int p0 = *(const unsigned int*)&Pb[((unsigned)r0.x << 7) + lo2];
        float w0 = __int_as_float(r0.y);
        a = __builtin_elementwise_fma((f32x2){w0, w0}, gelu2v((f32x2){bfh(p0), bfl(p0)} + q), a);
        wsum += w0;
    }
    *(ushort2*)&GAB[((unsigned)n << 7) + lo2] = make_ushort2(f2bf(a.x), f2bf(a.y));
    if (lane == 0) sw[n] = wsum;
}

// ---------------------------------------------------------------------------
// K3 (MFMA): fused update MLP, 32-row blocks, fragment-major B, with
// one-iteration-ahead register prefetch in both GEMM phases.
// ---------------------------------------------------------------------------
__global__ __launch_bounds__(256) void k3_mfma(
    const float* __restrict__ s, const ushort* __restrict__ GAB, const float* __restrict__ sw,
    const ushort* __restrict__ WUCF, const float* __restrict__ BV, const float* __restrict__ bu1,
    const ushort* __restrict__ WU2F, const float* __restrict__ bu2,
    float* __restrict__ out, int N)
{
    __shared__ __align__(16) short Asub[32 * 264];
    __shared__ __align__(16) short H2[32 * 136];
    __shared__ float SWs[32];
    int tid = threadIdx.x;
    int w = tid >> 6, l = tid & 63;
    int lr = l & 15, lkq = l >> 4;
    int lk = lkq * 8;
    int boff = (lr << 5) + (lkq << 3);
    int n0 = blockIdx.x * 32;

    if (tid < 32) SWs[tid] = (n0 + tid < N) ? sw[n0 + tid] : 0.f;

    {
        int ar = tid & 31;
        int kg = (tid >> 5) * 8;
        int arow = n0 + ar; if (arow >= N) arow = N - 1;
        #pragma unroll
        for (int c = 0; c < 4; ++c) {
            int k = c * 64 + kg;
            BF8 pk;
            if (k < 128) {
                const float* asrc = s + (size_t)arow * 128 + k;
                float4 f0 = *(const float4*)asrc;
                float4 f1 = *(const float4*)(asrc + 4);
                pk.u[0] = f2bf(f0.x); pk.u[1] = f2bf(f0.y); pk.u[2] = f2bf(f0.z); pk.u[3] = f2bf(f0.w);
                pk.u[4] = f2bf(f1.x); pk.u[5] = f2bf(f1.y); pk.u[6] = f2bf(f1.z); pk.u[7] = f2bf(f1.w);
            } else {
                pk.v = *(const bf16x8*)(GAB + (size_t)arow * 128 + (k - 128));
            }
            *(bf16x8*)&Asub[ar * 264 + k] = pk.v;
        }
    }
    __syncthreads();

    // ---- Phase A: K=256, prefetched
    f32x4 acc[2][2];
    #pragma unroll
    for (int i = 0; i < 2; ++i) { acc[i][0] = (f32x4){0,0,0,0}; acc[i][1] = (f32x4){0,0,0,0}; }

    bf16x8 bcur[2], a0c, a1c;
    #pragma unroll
    for (int ct = 0; ct < 2; ++ct)
        bcur[ct] = *(const bf16x8*)(WUCF + (size_t)((w * 2 + ct) * 8) * 512 + boff);
    a0c = *(const bf16x8*)&Asub[lr * 264 + lk];
    a1c = *(const bf16x8*)&Asub[(16 + lr) * 264 + lk];

    #pragma unroll
    for (int kk = 0; kk < 8; ++kk) {
        bf16x8 bn[2], a0n, a1n;
        if (kk < 7) {
            #pragma unroll
            for (int ct = 0; ct < 2; ++ct)
                bn[ct] = *(const bf16x8*)(WUCF + (size_t)((w * 2 + ct) * 8 + kk + 1) * 512 + boff);
            a0n = *(const bf16x8*)&Asub[lr * 264 + (kk + 1) * 32 + lk];
            a1n = *(const bf16x8*)&Asub[(16 + lr) * 264 + (kk + 1) * 32 + lk];
        }
        #pragma unroll
        for (int ct = 0; ct < 2; ++ct) {
            acc[0][ct] = __builtin_amdgcn_mfma_f32_16x16x32_bf16(a0c, bcur[ct], acc[0][ct], 0, 0, 0);
            acc[1][ct] = __builtin_amdgcn_mfma_f32_16x16x32_bf16(a1c, bcur[ct], acc[1][ct], 0, 0, 0);
        }
        if (kk < 7) {
            bcur[0] = bn[0]; bcur[1] = bn[1];
            a0c = a0n; a1c = a1n;
        }
    }

    int rbase = lkq * 4;
    #pragma unroll
    for (int ct = 0; ct < 2; ++ct) {
        int col = w * 32 + ct * 16 + lr;
        float b1 = bu1[col], bv = BV[col];
        #pragma unroll
        for (int rt = 0; rt < 2; ++rt) {
            #pragma unroll
            for (int r = 0; r < 4; ++r) {
                int row16 = rt * 16 + rbase + r;
                float v = acc[rt][ct][r] + b1 + SWs[row16] * bv;
                H2[row16 * 136 + col] = (short)f2bf(gelu_fast(v));
            }
        }
    }
    __syncthreads();

    // ---- Phase B: K=128, prefetched
    f32x4 acc2[2][2];
    #pragma unroll
    for (int i = 0; i < 2; ++i) { acc2[i][0] = (f32x4){0,0,0,0}; acc2[i][1] = (f32x4){0,0,0,0}; }

    bf16x8 b2c[2], h0c, h1c;
    #pragma unroll
    for (int ct = 0; ct < 2; ++ct)
        b2c[ct] = *(const bf16x8*)(WU2F + (size_t)((w * 2 + ct) * 4) * 512 + boff);
    h0c = *(const bf16x8*)&H2[lr * 136 + lk];
    h1c = *(const bf16x8*)&H2[(16 + lr) * 136 + lk];

    #pragma unroll
    for (int kk = 0; kk < 4; ++kk) {
        bf16x8 bn[2], h0n, h1n;
        if (kk < 3) {
            #pragma unroll
            for (int ct = 0; ct < 2; ++ct)
                bn[ct] = *(const bf16x8*)(WU2F + (size_t)((w * 2 + ct) * 4 + kk + 1) * 512 + boff);
            h0n = *(const bf16x8*)&H2[lr * 136 + (kk + 1) * 32 + lk];
            h1n = *(const bf16x8*)&H2[(16 + lr) * 136 + (kk + 1) * 32 + lk];
        }
        #pragma unroll
        for (int ct = 0; ct < 2; ++ct) {
            acc2[0][ct] = __builtin_amdgcn_mfma_f32_16x16x32_bf16(h0c, b2c[ct], acc2[0][ct], 0, 0, 0);
            acc2[1][ct] = __builtin_amdgcn_mfma_f32_16x16x32_bf16(h1c, b2c[ct], acc2[1][ct], 0, 0, 0);
        }
        if (kk < 3) {
            b2c[0] = bn[0]; b2c[1] = bn[1];
            h0c = h0n; h1c = h1n;
        }
    }

    #pragma unroll
    for (int ct = 0; ct < 2; ++ct) {
        int col = w * 32 + ct * 16 + lr;
        float b2 = bu2[col];
        #pragma unroll
        for (int rt = 0; rt < 2; ++rt) {
            #pragma unroll
            for (int r = 0; r < 4; ++r) {
                int row = n0 + rt * 16 + rbase + r;
                if (row < N) out[(size_t)row * 128 + col] = acc2[rt][ct][r] + b2;
            }
        }
    }
}

// ---------------------------------------------------------------------------
extern "C" void kernel_launch(void* const* d_in, const int* in_sizes, int n_in,
                              void* d_out, int out_size, void* d_ws, size_t ws_size,
                              hipStream_t stream) {
    const float* s    = (const float*)d_in[0];
    const float* x    = (const float*)d_in[1];
    const int*   ei   = (const int*)d_in[2];
    const float* ew   = (const float*)d_in[3];
    const float* t    = (const float*)d_in[4];
    const float* Wm1  = (const float*)d_in[5];
    const float* bm1  = (const float*)d_in[6];
    const float* Wm2  = (const float*)d_in[7];
    const float* bm2  = (const float*)d_in[8];
    const float* Wu1  = (const float*)d_in[9];
    const float* bu1  = (const float*)d_in[10];
    const float* Wu2  = (const float*)d_in[11];
    const float* bu2  = (const float*)d_in[12];

    int N = in_sizes[0] / 128;
    int E = in_sizes[2] / 2;
    const int* srcI = ei;
    const int* dstI = ei + E;
    int NP = (N + CHUNK - 1) & ~(CHUNK - 1);
    int C  = NP / CHUNK;

    // workspace layout (32-bit words)
    float* ws = (float*)d_ws;
    size_t off = 0;
    ushort* Pb   = (ushort*)(ws + off); off += (size_t)N * 64;
    ushort* Qb   = (ushort*)(ws + off); off += (size_t)N * 64;
    float*  SW   = ws + off; off += ((size_t)N + 63) & ~(size_t)63;
    ushort* GAB  = (ushort*)(ws + off); off += (size_t)N * 64;
    ushort* WC1F = (ushort*)(ws + off); off += (256 * 320) / 2;
    ushort* WUCF = (ushort*)(ws + off); off += (128 * 256) / 2;
    ushort* WU2F = (ushort*)(ws + off); off += (128 * 128) / 2;
    float*  BV   = ws + off; off += 128;
    int*    DEG  = (int*)(ws + off); off += (size_t)NP;
    int*    OFFS = (int*)(ws + off); off += (size_t)NP + 64;
    off = (off + 3) & ~(size_t)3;
    int*    CUR  = (int*)(ws + off); off += (size_t)NP;
    int*    CSUM = (int*)(ws + off); off += 128;
    int*    CBASE= (int*)(ws + off); off += 128;
    off = (off + 3) & ~(size_t)3;
    int2*   REC  = (int2*)(ws + off); off += (size_t)E * 2;

    // zero histogram, then fused weight-prep + histogram
    hipMemsetAsync(DEG, 0, (size_t)NP * sizeof(int), stream);
    int histBlocks = (E + 255) / 256;
    k_prep<<<512 + histBlocks, 256, 0, stream>>>(Wm1, Wu1, Wm2, bm2, Wu2, dstI, E,
                                                 WC1F, WUCF, WU2F, BV, DEG);

    // counting sort tail
    k_chunksum<<<C, 256, 0, stream>>>(DEG, CSUM);
    k_chunkscan<<<1, 64, 0, stream>>>(CSUM, CBASE, C, OFFS, N, E);
    k_chunkoffs<<<C, 256, 0, stream>>>(DEG, CBASE, OFFS, CUR);
    k_scatter<<<(E + 255) / 256, 256, 0, stream>>>(srcI, dstI, ew, CUR, REC, E);

    // node precompute (MFMA)
    int nb32 = (N + 31) / 32;
    k1_mfma<<<nb32, 256, 0, stream>>>(s, x, t, WC1F, bm1, Pb, Qb, N);

    // segmented aggregation (vector-f32x2 gelu, pipelined gathers)
    k_agg<<<(N + 3) / 4, 256, 0, stream>>>(Pb, Qb, REC, OFFS, GAB, SW, N);

    // update MLP (MFMA, fused, prefetched)
    k3_mfma<<<nb32, 256, 0, stream>>>(s, GAB, SW, WUCF, BV, bu1, WU2F, bu2, (float*)d_out, N);
}

// Round 16
// 207.794 us; speedup vs baseline: 1.0942x; 1.0737x over previous
//
#include <hip/hip_runtime.h>
#include <math.h>

#define NHID 128
#define CHUNK 1024

typedef __attribute__((ext_vector_type(8))) short bf16x8;
typedef __attribute__((ext_vector_type(4))) float f32x4;

union BF8 { ushort u[8]; bf16x8 v; };

__device__ __forceinline__ ushort f2bf(float f) {
    unsigned int u = __float_as_uint(f);
    u += 0x7FFFu + ((u >> 16) & 1u);      // round-to-nearest-even
    return (ushort)(u >> 16);
}
__device__ __forceinline__ float bfh(unsigned int v) { return __uint_as_float(v << 16); }
__device__ __forceinline__ float bfl(unsigned int v) { return __uint_as_float(v & 0xffff0000u); }

// Branch-free GELU (A&S 7.1.26 erf, max err ~1.5e-7) — exact-erf form, used in
// k3's epilogue (6.4M evals).  (pk-asm gelu: broken VOP3P semantics, banned.
// LDS-table: slower, r12. f32x2 vector-C: scalarized, neutral, r15.)
__device__ __forceinline__ float gelu_fast(float x) {
    float ax = fabsf(x);
    float t  = __builtin_amdgcn_rcpf(fmaf(0.23165493f, ax, 1.0f));
    float p  = t * fmaf(t, fmaf(t, fmaf(t, fmaf(t, 1.061405429f, -1.453152027f),
                                        1.421413741f), -0.284496736f), 0.254829592f);
    float e  = __builtin_amdgcn_exp2f(-0.7213475204f * ax * ax);
    float hax = 0.5f * ax;
    return fmaf(-hax, p * e, 0.5f * x + hax);
}

// tanh-form GELU, fully folded: 5 VALU + 2 trans (vs 12+2 for erf form).
//   gelu ~= 0.5x(1+tanh(0.7978845608(x+0.044715x^3)))
//         = x - x/(1+exp2(x*(2.3022094f + 0.10294540f*x^2)))
// (constants pre-scaled by 2*log2(e)); max dev from exact erf ~1e-3.
// Saturates gracefully: exp2 -> inf => gelu -> x ; exp2 -> 0 => gelu -> 0.
// Used ONLY in k_agg's 102M-eval edge loop (error budget analyzed r16).
__device__ __forceinline__ float gelu_tanh(float x) {
    float x2 = x * x;
    float z  = x * fmaf(0.10294540f, x2, 2.3022094f);
    float e  = __builtin_amdgcn_exp2f(z);
    float r  = __builtin_amdgcn_rcpf(1.0f + e);
    return fmaf(-x, r, x);
}

// ---------------------------------------------------------------------------
// Fused weight prep + edge histogram.  Fragment-major weights: element (c,k)
// of [C][K] -> ((c/16)*KK + k/32)*512 + (c%16)*32 + (k%32).
//   blocks 0-319   : WC1F   blocks 320-447 : WUCF + BV
//   blocks 448-511 : WU2F   blocks 512+    : histogram of dst into DEG
// ---------------------------------------------------------------------------
__global__ __launch_bounds__(256) void k_prep(
    const float* __restrict__ Wm1, const float* __restrict__ Wu1,
    const float* __restrict__ Wm2, const float* __restrict__ bm2,
    const float* __restrict__ Wu2, const int* __restrict__ dstI, int E,
    ushort* __restrict__ WC1F, ushort* __restrict__ WUCF,
    ushort* __restrict__ WU2F, float* __restrict__ BV, int* __restrict__ deg)
{
    int bid = blockIdx.x, tid = threadIdx.x;
    if (bid < 320) {                      // WC1F
        int idx = bid * 256 + tid;
        int c = idx / 320, k = idx % 320;
        float v;
        if (k < 128) {
            v = (c < 128) ? Wm1[k * 128 + c] : Wm1[(128 + k) * 128 + (c - 128)];
        } else if (k < 256) {
            int kk = k - 128;
            v = (c < 128) ? Wm1[(256 + kk) * 128 + c] : -Wm1[(256 + kk) * 128 + (c - 128)];
        } else {
            int kk = k - 256;
            v = (c < 128) ? 0.0f : Wm1[(384 + kk) * 128 + (c - 128)];
        }
        int dst = ((c >> 4) * 10 + (k >> 5)) * 512 + ((c & 15) << 5) + (k & 31);
        WC1F[dst] = f2bf(v);
    } else if (bid < 448) {               // WUCF + BV
        int idx = (bid - 320) * 256 + tid;
        int c = idx >> 8, k = idx & 255;
        float v;
        if (k < 128) {
            v = Wu1[k * 128 + c];
        } else {
            int i = k - 128;
            float acc = 0.f;
            for (int j = 0; j < 128; ++j) acc += Wm2[i * 128 + j] * Wu1[(128 + j) * 128 + c];
            v = acc;
        }
        int dst = ((c >> 4) * 8 + (k >> 5)) * 512 + ((c & 15) << 5) + (k & 31);
        WUCF[dst] = f2bf(v);
        if (idx < 128) {
            float acc = 0.f;
            for (int j = 0; j < 128; ++j) acc += bm2[j] * Wu1[(128 + j) * 128 + idx];
            BV[idx] = acc;
        }
    } else if (bid < 512) {               // WU2F
        int idx = (bid - 448) * 256 + tid;
        int c = idx >> 7, k = idx & 127;
        int dst = ((c >> 4) * 4 + (k >> 5)) * 512 + ((c & 15) << 5) + (k & 31);
        WU2F[dst] = f2bf(Wu2[k * 128 + c]);
    } else {                              // histogram
        int i = (bid - 512) * 256 + tid;
        if (i < E) atomicAdd(&deg[dstI[i]], 1);
    }
}

// ---------------------------------------------------------------------------
// Counting sort tail: chunksum -> chunkscan -> chunkoffs -> scatter
// ---------------------------------------------------------------------------
__global__ __launch_bounds__(256) void k_chunksum(const int* __restrict__ deg,
                                                  int* __restrict__ csum) {
    int c = blockIdx.x, tid = threadIdx.x;
    int4 v = ((const int4*)(deg + (size_t)c * CHUNK))[tid];
    int ts = v.x + v.y + v.z + v.w;
    #pragma unroll
    for (int d = 1; d < 64; d <<= 1) ts += __shfl_xor(ts, d);
    __shared__ int wsum[4];
    if ((tid & 63) == 0) wsum[tid >> 6] = ts;
    __syncthreads();
    if (tid == 0) csum[c] = wsum[0] + wsum[1] + wsum[2] + wsum[3];
}
__global__ void k_chunkscan(const int* __restrict__ csum, int* __restrict__ cbase,
                            int C, int* __restrict__ offs, int N, int E) {
    int lane = threadIdx.x;   // 64
    int carry = 0;
    for (int b = 0; b < C; b += 64) {
        int v = (b + lane < C) ? csum[b + lane] : 0;
        int incl = v;
        #pragma unroll
        for (int d = 1; d < 64; d <<= 1) {
            int t = __shfl_up(incl, d);
            if (lane >= d) incl += t;
        }
        if (b + lane < C) cbase[b + lane] = carry + incl - v;
        carry += __shfl(incl, 63);
    }
    if (lane == 0) offs[N] = E;
}
__global__ __launch_bounds__(256) void k_chunkoffs(const int* __restrict__ deg,
                                                   const int* __restrict__ cbase,
                                                   int* __restrict__ offs,
                                                   int* __restrict__ cursor) {
    int c = blockIdx.x, tid = threadIdx.x;
    int lane = tid & 63, wid = tid >> 6;
    int4 v = ((const int4*)(deg + (size_t)c * CHUNK))[tid];
    int t0 = v.x, t1 = t0 + v.y, t2 = t1 + v.z, ts = t2 + v.w;
    int incl = ts;
    #pragma unroll
    for (int d = 1; d < 64; d <<= 1) {
        int t = __shfl_up(incl, d);
        if (lane >= d) incl += t;
    }
    __shared__ int wz[4];
    if (lane == 63) wz[wid] = incl;
    __syncthreads();
    int wbase = 0;
    for (int k2 = 0; k2 < wid; ++k2) wbase += wz[k2];
    int eb = cbase[c] + wbase + incl - ts;
    int4 o = make_int4(eb, eb + t0, eb + t1, eb + t2);
    ((int4*)(offs + (size_t)c * CHUNK))[tid] = o;
    ((int4*)(cursor + (size_t)c * CHUNK))[tid] = o;
}
__global__ void k_scatter(const int* __restrict__ src, const int* __restrict__ dst,
                          const float* __restrict__ w, int* __restrict__ cursor,
                          int2* __restrict__ rec, int E) {
    int i = blockIdx.x * blockDim.x + threadIdx.x;
    if (i < E) {
        int d = dst[i];
        int pos = atomicAdd(&cursor[d], 1);
        rec[pos] = make_int2(src[i], __float_as_int(w[i]));
    }
}

// ---------------------------------------------------------------------------
// K1 (MFMA): [P|Q] = [s|x|t] @ Wc1.  32-row blocks, A staged once, B frags
// 1024B coalesced loads from fragment-major WC1F (L2-resident), one-ahead
// register prefetch.  NOT fused with scatter (r11) or agg (r14).
// ---------------------------------------------------------------------------
__global__ __launch_bounds__(256) void k1_mfma(
    const float* __restrict__ s, const float* __restrict__ x, const float* __restrict__ t,
    const ushort* __restrict__ WC1F, const float* __restrict__ bm1,
    ushort* __restrict__ Pb, ushort* __restrict__ Qb, int N)
{
    __shared__ __align__(16) short Asub[32 * 328];
    int tid = threadIdx.x;
    int w = tid >> 6, l = tid & 63;
    int lr = l & 15, lkq = l >> 4;
    int lk = lkq * 8;
    int boff = (lr << 5) + (lkq << 3);
    int n0 = blockIdx.x * 32;

    {
        int ar = tid & 31;
        int kg = (tid >> 5) * 8;
        int arow = n0 + ar; if (arow >= N) arow = N - 1;
        #pragma unroll
        for (int c = 0; c < 5; ++c) {
            int k = c * 64 + kg;
            const float* asrc;
            if (k < 128)      asrc = s + (size_t)arow * 128 + k;
            else if (k < 256) asrc = x + (size_t)arow * 128 + (k - 128);
            else              asrc = t + (size_t)arow * 64 + (k - 256);
            float4 f0 = *(const float4*)asrc;
            float4 f1 = *(const float4*)(asrc + 4);
            BF8 pk;
            pk.u[0] = f2bf(f0.x); pk.u[1] = f2bf(f0.y); pk.u[2] = f2bf(f0.z); pk.u[3] = f2bf(f0.w);
            pk.u[4] = f2bf(f1.x); pk.u[5] = f2bf(f1.y); pk.u[6] = f2bf(f1.z); pk.u[7] = f2bf(f1.w);
            *(bf16x8*)&Asub[ar * 328 + k] = pk.v;
        }
    }
    __syncthreads();

    f32x4 acc[2][4];
    #pragma unroll
    for (int i = 0; i < 2; ++i)
        #pragma unroll
        for (int j = 0; j < 4; ++j) acc[i][j] = (f32x4){0.f, 0.f, 0.f, 0.f};

    const ushort* wbase = WC1F + boff;
    bf16x8 bcur[4], a0c, a1c;
    #pragma unroll
    for (int ct = 0; ct < 4; ++ct)
        bcur[ct] = *(const bf16x8*)(wbase + (size_t)((w * 4 + ct) * 10) * 512);
    a0c = *(const bf16x8*)&Asub[lr * 328 + lk];
    a1c = *(const bf16x8*)&Asub[(16 + lr) * 328 + lk];

    #pragma unroll
    for (int kk = 0; kk < 10; ++kk) {
        bf16x8 bn[4], a0n, a1n;
        if (kk < 9) {
            #pragma unroll
            for (int ct = 0; ct < 4; ++ct)
                bn[ct] = *(const bf16x8*)(wbase + (size_t)((w * 4 + ct) * 10 + kk + 1) * 512);
            a0n = *(const bf16x8*)&Asub[lr * 328 + (kk + 1) * 32 + lk];
            a1n = *(const bf16x8*)&Asub[(16 + lr) * 328 + (kk + 1) * 32 + lk];
        }
        #pragma unroll
        for (int ct = 0; ct < 4; ++ct) {
            acc[0][ct] = __builtin_amdgcn_mfma_f32_16x16x32_bf16(a0c, bcur[ct], acc[0][ct], 0, 0, 0);
            acc[1][ct] = __builtin_amdgcn_mfma_f32_16x16x32_bf16(a1c, bcur[ct], acc[1][ct], 0, 0, 0);
        }
        if (kk < 9) {
            #pragma unroll
            for (int ct = 0; ct < 4; ++ct) bcur[ct] = bn[ct];
            a0c = a0n; a1c = a1n;
        }
    }

    int rbase = lkq * 4;
    #pragma unroll
    for (int ct = 0; ct < 4; ++ct) {
        int col = w * 64 + ct * 16 + lr;
        float bb = (col >= 128) ? bm1[col - 128] : 0.f;
        #pragma unroll
        for (int rt = 0; rt < 2; ++rt) {
            #pragma unroll
            for (int r = 0; r < 4; ++r) {
                int row = n0 + rt * 16 + rbase + r;
                if (row < N) {
                    float v = acc[rt][ct][r];
                    if (col < 128) Pb[(size_t)row * 128 + col] = f2bf(v);
                    else           Qb[(size_t)row * 128 + (col - 128)] = f2bf(v + bb);
                }
            }
        }
    }
}

// ---------------------------------------------------------------------------
// K_agg: segmented reduction, one wave per dst node, 2 ch/lane.
// tanh-form gelu (5 VALU + 2 trans); software-pipelined gathers; 32-bit offsets.
// ---------------------------------------------------------------------------
__global__ __launch_bounds__(256) void k_agg(
    const ushort* __restrict__ Pb, const ushort* __restrict__ Qb,
    const int2* __restrict__ rec, const int* __restrict__ offs,
    ushort* __restrict__ GAB, float* __restrict__ sw, int N)
{
    int n = blockIdx.x * 4 + (threadIdx.x >> 6);
    if (n >= N) return;
    int lane = threadIdx.x & 63;
    unsigned lo2 = (unsigned)(lane << 1);
    int beg = __builtin_amdgcn_readfirstlane(offs[n]);
    int end = __builtin_amdgcn_readfirstlane(offs[n + 1]);
    unsigned int qv = *(const unsigned int*)&Qb[((unsigned)n << 7) + lo2];
    float qx = bfh(qv), qy = bfl(qv);
    float a0 = 0.f, a1 = 0.f, wsum = 0.f;
    int j = beg;
    if (j + 4 <= end) {
        int2 r0 = rec[j], r1 = rec[j + 1], r2 = rec[j + 2], r3 = rec[j + 3];
        unsigned int p0 = *(const unsigned int*)&Pb[((unsigned)r0.x << 7) + lo2];
        unsigned int p1 = *(const unsigned int*)&Pb[((unsigned)r1.x << 7) + lo2];
        unsigned int p2 = *(const unsigned int*)&Pb[((unsigned)r2.x << 7) + lo2];
        unsigned int p3 = *(const unsigned int*)&Pb[((unsigned)r3.x << 7) + lo2];
        j += 4;
        while (j + 4 <= end) {
            int2 s0 = rec[j], s1 = rec[j + 1], s2 = rec[j + 2], s3 = rec[j + 3];
            unsigned int n0_ = *(const unsigned int*)&Pb[((unsigned)s0.x << 7) + lo2];
            unsigned int n1_ = *(const unsigned int*)&Pb[((unsigned)s1.x << 7) + lo2];
            unsigned int n2_ = *(const unsigned int*)&Pb[((unsigned)s2.x << 7) + lo2];
            unsigned int n3_ = *(const unsigned int*)&Pb[((unsigned)s3.x << 7) + lo2];
            float w0 = __int_as_float(r0.y), w1 = __int_as_float(r1.y);
            float w2 = __int_as_float(r2.y), w3 = __int_as_float(r3.y);
            a0 = fmaf(w0, gelu_tanh(bfh(p0) + qx), a0);
            a1 = fmaf(w0, gelu_tanh(bfl(p0) + qy), a1);
            a0 = fmaf(w1, gelu_tanh(bfh(p1) + qx), a0);
            a1 = fmaf(w1, gelu_tanh(bfl(p1) + qy), a1);
            a0 = fmaf(w2, gelu_tanh(bfh(p2) + qx), a0);
            a1 = fmaf(w2, gelu_tanh(bfl(p2) + qy), a1);
            a0 = fmaf(w3, gelu_tanh(bfh(p3) + qx), a0);
            a1 = fmaf(w3, gelu_tanh(bfl(p3) + qy), a1);
            wsum += (w0 + w1) + (w2 + w3);
            r0 = s0; r1 = s1; r2 = s2; r3 = s3;
            p0 = n0_; p1 = n1_; p2 = n2_; p3 = n3_;
            j += 4;
        }
        float w0 = __int_as_float(r0.y), w1 = __int_as_float(r1.y);
        float w2 = __int_as_float(r2.y), w3 = __int_as_float(r3.y);
        a0 = fmaf(w0, gelu_tanh(bfh(p0) + qx), a0);
        a1 = fmaf(w0, gelu_tanh(bfl(p0) + qy), a1);
        a0 = fmaf(w1, gelu_tanh(bfh(p1) + qx), a0);
        a1 = fmaf(w1, gelu_tanh(bfl(p1) + qy), a1);
        a0 = fmaf(w2, gelu_tanh(bfh(p2) + qx), a0);
        a1 = fmaf(w2, gelu_tanh(bfl(p2) + qy), a1);
        a0 = fmaf(w3, gelu_tanh(bfh(p3) + qx), a0);
        a1 = fmaf(w3, gelu_tanh(bfl(p3) + qy), a1);
        wsum += (w0 + w1) + (w2 + w3);
    }
    for (; j < end; ++j) {
        int2 r0 = rec[j];
        unsigned int p0 = *(const unsigned int*)&Pb[((unsigned)r0.x << 7) + lo2];
        float w0 = __int_as_float(r0.y);
        a0 = fmaf(w0, gelu_tanh(bfh(p0) + qx), a0);
        a1 = fmaf(w0, gelu_tanh(bfl(p0) + qy), a1);
        wsum += w0;
    }
    *(ushort2*)&GAB[((unsigned)n << 7) + lo2] = make_ushort2(f2bf(a0), f2bf(a1));
    if (lane == 0) sw[n] = wsum;
}

// ---------------------------------------------------------------------------
// K3 (MFMA): fused update MLP, 32-row blocks, fragment-major B, with
// one-iteration-ahead register prefetch in both GEMM phases.
// ---------------------------------------------------------------------------
__global__ __launch_bounds__(256) void k3_mfma(
    const float* __restrict__ s, const ushort* __restrict__ GAB, const float* __restrict__ sw,
    const ushort* __restrict__ WUCF, const float* __restrict__ BV, const float* __restrict__ bu1,
    const ushort* __restrict__ WU2F, const float* __restrict__ bu2,
    float* __restrict__ out, int N)
{
    __shared__ __align__(16) short Asub[32 * 264];
    __shared__ __align__(16) short H2[32 * 136];
    __shared__ float SWs[32];
    int tid = threadIdx.x;
    int w = tid >> 6, l = tid & 63;
    int lr = l & 15, lkq = l >> 4;
    int lk = lkq * 8;
    int boff = (lr << 5) + (lkq << 3);
    int n0 = blockIdx.x * 32;

    if (tid < 32) SWs[tid] = (n0 + tid < N) ? sw[n0 + tid] : 0.f;

    {
        int ar = tid & 31;
        int kg = (tid >> 5) * 8;
        int arow = n0 + ar; if (arow >= N) arow = N - 1;
        #pragma unroll
        for (int c = 0; c < 4; ++c) {
            int k = c * 64 + kg;
            BF8 pk;
            if (k < 128) {
                const float* asrc = s + (size_t)arow * 128 + k;
                float4 f0 = *(const float4*)asrc;
                float4 f1 = *(const float4*)(asrc + 4);
                pk.u[0] = f2bf(f0.x); pk.u[1] = f2bf(f0.y); pk.u[2] = f2bf(f0.z); pk.u[3] = f2bf(f0.w);
                pk.u[4] = f2bf(f1.x); pk.u[5] = f2bf(f1.y); pk.u[6] = f2bf(f1.z); pk.u[7] = f2bf(f1.w);
            } else {
                pk.v = *(const bf16x8*)(GAB + (size_t)arow * 128 + (k - 128));
            }
            *(bf16x8*)&Asub[ar * 264 + k] = pk.v;
        }
    }
    __syncthreads();

    // ---- Phase A: K=256, prefetched
    f32x4 acc[2][2];
    #pragma unroll
    for (int i = 0; i < 2; ++i) { acc[i][0] = (f32x4){0,0,0,0}; acc[i][1] = (f32x4){0,0,0,0}; }

    bf16x8 bcur[2], a0c, a1c;
    #pragma unroll
    for (int ct = 0; ct < 2; ++ct)
        bcur[ct] = *(const bf16x8*)(WUCF + (size_t)((w * 2 + ct) * 8) * 512 + boff);
    a0c = *(const bf16x8*)&Asub[lr * 264 + lk];
    a1c = *(const bf16x8*)&Asub[(16 + lr) * 264 + lk];

    #pragma unroll
    for (int kk = 0; kk < 8; ++kk) {
        bf16x8 bn[2], a0n, a1n;
        if (kk < 7) {
            #pragma unroll
            for (int ct = 0; ct < 2; ++ct)
                bn[ct] = *(const bf16x8*)(WUCF + (size_t)((w * 2 + ct) * 8 + kk + 1) * 512 + boff);
            a0n = *(const bf16x8*)&Asub[lr * 264 + (kk + 1) * 32 + lk];
            a1n = *(const bf16x8*)&Asub[(16 + lr) * 264 + (kk + 1) * 32 + lk];
        }
        #pragma unroll
        for (int ct = 0; ct < 2; ++ct) {
            acc[0][ct] = __builtin_amdgcn_mfma_f32_16x16x32_bf16(a0c, bcur[ct], acc[0][ct], 0, 0, 0);
            acc[1][ct] = __builtin_amdgcn_mfma_f32_16x16x32_bf16(a1c, bcur[ct], acc[1][ct], 0, 0, 0);
        }
        if (kk < 7) {
            bcur[0] = bn[0]; bcur[1] = bn[1];
            a0c = a0n; a1c = a1n;
        }
    }

    int rbase = lkq * 4;
    #pragma unroll
    for (int ct = 0; ct < 2; ++ct) {
        int col = w * 32 + ct * 16 + lr;
        float b1 = bu1[col], bv = BV[col];
        #pragma unroll
        for (int rt = 0; rt < 2; ++rt) {
            #pragma unroll
            for (int r = 0; r < 4; ++r) {
                int row16 = rt * 16 + rbase + r;
                float v = acc[rt][ct][r] + b1 + SWs[row16] * bv;
                H2[row16 * 136 + col] = (short)f2bf(gelu_fast(v));
            }
        }
    }
    __syncthreads();

    // ---- Phase B: K=128, prefetched
    f32x4 acc2[2][2];
    #pragma unroll
    for (int i = 0; i < 2; ++i) { acc2[i][0] = (f32x4){0,0,0,0}; acc2[i][1] = (f32x4){0,0,0,0}; }

    bf16x8 b2c[2], h0c, h1c;
    #pragma unroll
    for (int ct = 0; ct < 2; ++ct)
        b2c[ct] = *(const bf16x8*)(WU2F + (size_t)((w * 2 + ct) * 4) * 512 + boff);
    h0c = *(const bf16x8*)&H2[lr * 136 + lk];
    h1c = *(const bf16x8*)&H2[(16 + lr) * 136 + lk];

    #pragma unroll
    for (int kk = 0; kk < 4; ++kk) {
        bf16x8 bn[2], h0n, h1n;
        if (kk < 3) {
            #pragma unroll
            for (int ct = 0; ct < 2; ++ct)
                bn[ct] = *(const bf16x8*)(WU2F + (size_t)((w * 2 + ct) * 4 + kk + 1) * 512 + boff);
            h0n = *(const bf16x8*)&H2[lr * 136 + (kk + 1) * 32 + lk];
            h1n = *(const bf16x8*)&H2[(16 + lr) * 136 + (kk + 1) * 32 + lk];
        }
        #pragma unroll
        for (int ct = 0; ct < 2; ++ct) {
            acc2[0][ct] = __builtin_amdgcn_mfma_f32_16x16x32_bf16(h0c, b2c[ct], acc2[0][ct], 0, 0, 0);
            acc2[1][ct] = __builtin_amdgcn_mfma_f32_16x16x32_bf16(h1c, b2c[ct], acc2[1][ct], 0, 0, 0);
        }
        if (kk < 3) {
            b2c[0] = bn[0]; b2c[1] = bn[1];
            h0c = h0n; h1c = h1n;
        }
    }

    #pragma unroll
    for (int ct = 0; ct < 2; ++ct) {
        int col = w * 32 + ct * 16 + lr;
        float b2 = bu2[col];
        #pragma unroll
        for (int rt = 0; rt < 2; ++rt) {
            #pragma unroll
            for (int r = 0; r < 4; ++r) {
                int row = n0 + rt * 16 + rbase + r;
                if (row < N) out[(size_t)row * 128 + col] = acc2[rt][ct][r] + b2;
            }
        }
    }
}

// ---------------------------------------------------------------------------
extern "C" void kernel_launch(void* const* d_in, const int* in_sizes, int n_in,
                              void* d_out, int out_size, void* d_ws, size_t ws_size,
                              hipStream_t stream) {
    const float* s    = (const float*)d_in[0];
    const float* x    = (const float*)d_in[1];
    const int*   ei   = (const int*)d_in[2];
    const float* ew   = (const float*)d_in[3];
    const float* t    = (const float*)d_in[4];
    const float* Wm1  = (const float*)d_in[5];
    const float* bm1  = (const float*)d_in[6];
    const float* Wm2  = (const float*)d_in[7];
    const float* bm2  = (const float*)d_in[8];
    const float* Wu1  = (const float*)d_in[9];
    const float* bu1  = (const float*)d_in[10];
    const float* Wu2  = (const float*)d_in[11];
    const float* bu2  = (const float*)d_in[12];

    int N = in_sizes[0] / 128;
    int E = in_sizes[2] / 2;
    const int* srcI = ei;
    const int* dstI = ei + E;
    int NP = (N + CHUNK - 1) & ~(CHUNK - 1);
    int C  = NP / CHUNK;

    // workspace layout (32-bit words)
    float* ws = (float*)d_ws;
    size_t off = 0;
    ushort* Pb   = (ushort*)(ws + off); off += (size_t)N * 64;
    ushort* Qb   = (ushort*)(ws + off); off += (size_t)N * 64;
    float*  SW   = ws + off; off += ((size_t)N + 63) & ~(size_t)63;
    ushort* GAB  = (ushort*)(ws + off); off += (size_t)N * 64;
    ushort* WC1F = (ushort*)(ws + off); off += (256 * 320) / 2;
    ushort* WUCF = (ushort*)(ws + off); off += (128 * 256) / 2;
    ushort* WU2F = (ushort*)(ws + off); off += (128 * 128) / 2;
    float*  BV   = ws + off; off += 128;
    int*    DEG  = (int*)(ws + off); off += (size_t)NP;
    int*    OFFS = (int*)(ws + off); off += (size_t)NP + 64;
    off = (off + 3) & ~(size_t)3;
    int*    CUR  = (int*)(ws + off); off += (size_t)NP;
    int*    CSUM = (int*)(ws + off); off += 128;
    int*    CBASE= (int*)(ws + off); off += 128;
    off = (off + 3) & ~(size_t)3;
    int2*   REC  = (int2*)(ws + off); off += (size_t)E * 2;

    // zero histogram, then fused weight-prep + histogram
    hipMemsetAsync(DEG, 0, (size_t)NP * sizeof(int), stream);
    int histBlocks = (E + 255) / 256;
    k_prep<<<512 + histBlocks, 256, 0, stream>>>(Wm1, Wu1, Wm2, bm2, Wu2, dstI, E,
                                                 WC1F, WUCF, WU2F, BV, DEG);

    // counting sort tail
    k_chunksum<<<C, 256, 0, stream>>>(DEG, CSUM);
    k_chunkscan<<<1, 64, 0, stream>>>(CSUM, CBASE, C, OFFS, N, E);
    k_chunkoffs<<<C, 256, 0, stream>>>(DEG, CBASE, OFFS, CUR);
    k_scatter<<<(E + 255) / 256, 256, 0, stream>>>(srcI, dstI, ew, CUR, REC, E);

    // node precompute (MFMA)
    int nb32 = (N + 31) / 32;
    k1_mfma<<<nb32, 256, 0, stream>>>(s, x, t, WC1F, bm1, Pb, Qb, N);

    // segmented aggregation (tanh gelu, pipelined gathers)
    k_agg<<<(N + 3) / 4, 256, 0, stream>>>(Pb, Qb, REC, OFFS, GAB, SW, N);

    // update MLP (MFMA, fused, prefetched)
    k3_mfma<<<nb32, 256, 0, stream>>>(s, GAB, SW, WUCF, BV, bu1, WU2F, bu2, (float*)d_out, N);
}

// Round 17
// 168.464 us; speedup vs baseline: 1.3497x; 1.2335x over previous
//
#include <hip/hip_runtime.h>
#include <math.h>

#define NHID 128
#define CHUNK 1024

typedef __attribute__((ext_vector_type(8))) short bf16x8;
typedef __attribute__((ext_vector_type(4))) float f32x4;

union BF8 { ushort u[8]; bf16x8 v; };

__device__ __forceinline__ ushort f2bf(float f) {
    unsigned int u = __float_as_uint(f);
    u += 0x7FFFu + ((u >> 16) & 1u);      // round-to-nearest-even
    return (ushort)(u >> 16);
}
__device__ __forceinline__ float bfh(unsigned int v) { return __uint_as_float(v << 16); }
__device__ __forceinline__ float bfl(unsigned int v) { return __uint_as_float(v & 0xffff0000u); }

// Exact-erf GELU (A&S 7.1.26, max err ~1.5e-7) — k3 epilogue (6.4M evals).
__device__ __forceinline__ float gelu_fast(float x) {
    float ax = fabsf(x);
    float t  = __builtin_amdgcn_rcpf(fmaf(0.23165493f, ax, 1.0f));
    float p  = t * fmaf(t, fmaf(t, fmaf(t, fmaf(t, 1.061405429f, -1.453152027f),
                                        1.421413741f), -0.284496736f), 0.254829592f);
    float e  = __builtin_amdgcn_exp2f(-0.7213475204f * ax * ax);
    float hax = 0.5f * ax;
    return fmaf(-hax, p * e, 0.5f * x + hax);
}

// tanh-form GELU, folded to 5 VALU + 2 trans (r16: −15us on k_agg, absmax
// unchanged).  gelu ~= x - x/(1+exp2(x*(2.3022094 + 0.10294540*x^2))).
__device__ __forceinline__ float gelu_tanh(float x) {
    float x2 = x * x;
    float z  = x * fmaf(0.10294540f, x2, 2.3022094f);
    float e  = __builtin_amdgcn_exp2f(z);
    float r  = __builtin_amdgcn_rcpf(1.0f + e);
    return fmaf(-x, r, x);
}

// ---------------------------------------------------------------------------
// Fused weight prep + edge histogram WITH RANK CAPTURE.
//   blocks 0-319   : WC1F   blocks 320-447 : WUCF + BV
//   blocks 448-511 : WU2F   blocks 512+    : rank[i] = atomicAdd(&deg[dst],1)
// Fragment-major weights: (c,k) -> ((c/16)*KK + k/32)*512 + (c%16)*32 + (k%31).
// ---------------------------------------------------------------------------
__global__ __launch_bounds__(256) void k_prep(
    const float* __restrict__ Wm1, const float* __restrict__ Wu1,
    const float* __restrict__ Wm2, const float* __restrict__ bm2,
    const float* __restrict__ Wu2, const int* __restrict__ dstI, int E,
    ushort* __restrict__ WC1F, ushort* __restrict__ WUCF,
    ushort* __restrict__ WU2F, float* __restrict__ BV,
    int* __restrict__ deg, int* __restrict__ rank)
{
    int bid = blockIdx.x, tid = threadIdx.x;
    if (bid < 320) {                      // WC1F
        int idx = bid * 256 + tid;
        int c = idx / 320, k = idx % 320;
        float v;
        if (k < 128) {
            v = (c < 128) ? Wm1[k * 128 + c] : Wm1[(128 + k) * 128 + (c - 128)];
        } else if (k < 256) {
            int kk = k - 128;
            v = (c < 128) ? Wm1[(256 + kk) * 128 + c] : -Wm1[(256 + kk) * 128 + (c - 128)];
        } else {
            int kk = k - 256;
            v = (c < 128) ? 0.0f : Wm1[(384 + kk) * 128 + (c - 128)];
        }
        int dst = ((c >> 4) * 10 + (k >> 5)) * 512 + ((c & 15) << 5) + (k & 31);
        WC1F[dst] = f2bf(v);
    } else if (bid < 448) {               // WUCF + BV
        int idx = (bid - 320) * 256 + tid;
        int c = idx >> 8, k = idx & 255;
        float v;
        if (k < 128) {
            v = Wu1[k * 128 + c];
        } else {
            int i = k - 128;
            float acc = 0.f;
            for (int j = 0; j < 128; ++j) acc += Wm2[i * 128 + j] * Wu1[(128 + j) * 128 + c];
            v = acc;
        }
        int dst = ((c >> 4) * 8 + (k >> 5)) * 512 + ((c & 15) << 5) + (k & 31);
        WUCF[dst] = f2bf(v);
        if (idx < 128) {
            float acc = 0.f;
            for (int j = 0; j < 128; ++j) acc += bm2[j] * Wu1[(128 + j) * 128 + idx];
            BV[idx] = acc;
        }
    } else if (bid < 512) {               // WU2F
        int idx = (bid - 448) * 256 + tid;
        int c = idx >> 7, k = idx & 127;
        int dst = ((c >> 4) * 4 + (k >> 5)) * 512 + ((c & 15) << 5) + (k & 31);
        WU2F[dst] = f2bf(Wu2[k * 128 + c]);
    } else {                              // histogram + rank capture
        int i = (bid - 512) * 256 + tid;
        if (i < E) rank[i] = atomicAdd(&deg[dstI[i]], 1);
    }
}

// ---------------------------------------------------------------------------
// Counting sort tail: chunksum -> chunkscan -> chunkoffs -> scatter (no atomics)
// ---------------------------------------------------------------------------
__global__ __launch_bounds__(256) void k_chunksum(const int* __restrict__ deg,
                                                  int* __restrict__ csum) {
    int c = blockIdx.x, tid = threadIdx.x;
    int4 v = ((const int4*)(deg + (size_t)c * CHUNK))[tid];
    int ts = v.x + v.y + v.z + v.w;
    #pragma unroll
    for (int d = 1; d < 64; d <<= 1) ts += __shfl_xor(ts, d);
    __shared__ int wsum[4];
    if ((tid & 63) == 0) wsum[tid >> 6] = ts;
    __syncthreads();
    if (tid == 0) csum[c] = wsum[0] + wsum[1] + wsum[2] + wsum[3];
}
__global__ void k_chunkscan(const int* __restrict__ csum, int* __restrict__ cbase,
                            int C, int* __restrict__ offs, int N, int E) {
    int lane = threadIdx.x;   // 64
    int carry = 0;
    for (int b = 0; b < C; b += 64) {
        int v = (b + lane < C) ? csum[b + lane] : 0;
        int incl = v;
        #pragma unroll
        for (int d = 1; d < 64; d <<= 1) {
            int t = __shfl_up(incl, d);
            if (lane >= d) incl += t;
        }
        if (b + lane < C) cbase[b + lane] = carry + incl - v;
        carry += __shfl(incl, 63);
    }
    if (lane == 0) offs[N] = E;
}
__global__ __launch_bounds__(256) void k_chunkoffs(const int* __restrict__ deg,
                                                   const int* __restrict__ cbase,
                                                   int* __restrict__ offs) {
    int c = blockIdx.x, tid = threadIdx.x;
    int lane = tid & 63, wid = tid >> 6;
    int4 v = ((const int4*)(deg + (size_t)c * CHUNK))[tid];
    int t0 = v.x, t1 = t0 + v.y, t2 = t1 + v.z, ts = t2 + v.w;
    int incl = ts;
    #pragma unroll
    for (int d = 1; d < 64; d <<= 1) {
        int t = __shfl_up(incl, d);
        if (lane >= d) incl += t;
    }
    __shared__ int wz[4];
    if (lane == 63) wz[wid] = incl;
    __syncthreads();
    int wbase = 0;
    for (int k2 = 0; k2 < wid; ++k2) wbase += wz[k2];
    int eb = cbase[c] + wbase + incl - ts;
    ((int4*)(offs + (size_t)c * CHUNK))[tid] = make_int4(eb, eb + t0, eb + t1, eb + t2);
}
// Scatter without atomics: pos = offs[dst] + rank (rank captured in k_prep).
__global__ void k_scatter(const int* __restrict__ src, const int* __restrict__ dst,
                          const float* __restrict__ w, const int* __restrict__ offs,
                          const int* __restrict__ rank, int2* __restrict__ rec, int E) {
    int i = blockIdx.x * blockDim.x + threadIdx.x;
    if (i < E) {
        int pos = offs[dst[i]] + rank[i];
        rec[pos] = make_int2(src[i], __float_as_int(w[i]));
    }
}

// ---------------------------------------------------------------------------
// K1 (MFMA): [P|Q] = [s|x|t] @ Wc1.  32-row blocks, A staged once, B frags
// 1024B coalesced loads from fragment-major WC1F (L2-resident), one-ahead
// register prefetch.  NOT fused with scatter (r11) or agg (r14).
// ---------------------------------------------------------------------------
__global__ __launch_bounds__(256) void k1_mfma(
    const float* __restrict__ s, const float* __restrict__ x, const float* __restrict__ t,
    const ushort* __restrict__ WC1F, const float* __restrict__ bm1,
    ushort* __restrict__ Pb, ushort* __restrict__ Qb, int N)
{
    __shared__ __align__(16) short Asub[32 * 328];
    int tid = threadIdx.x;
    int w = tid >> 6, l = tid & 63;
    int lr = l & 15, lkq = l >> 4;
    int lk = lkq * 8;
    int boff = (lr << 5) + (lkq << 3);
    int n0 = blockIdx.x * 32;

    {
        int ar = tid & 31;
        int kg = (tid >> 5) * 8;
        int arow = n0 + ar; if (arow >= N) arow = N - 1;
        #pragma unroll
        for (int c = 0; c < 5; ++c) {
            int k = c * 64 + kg;
            const float* asrc;
            if (k < 128)      asrc = s + (size_t)arow * 128 + k;
            else if (k < 256) asrc = x + (size_t)arow * 128 + (k - 128);
            else              asrc = t + (size_t)arow * 64 + (k - 256);
            float4 f0 = *(const float4*)asrc;
            float4 f1 = *(const float4*)(asrc + 4);
            BF8 pk;
            pk.u[0] = f2bf(f0.x); pk.u[1] = f2bf(f0.y); pk.u[2] = f2bf(f0.z); pk.u[3] = f2bf(f0.w);
            pk.u[4] = f2bf(f1.x); pk.u[5] = f2bf(f1.y); pk.u[6] = f2bf(f1.z); pk.u[7] = f2bf(f1.w);
            *(bf16x8*)&Asub[ar * 328 + k] = pk.v;
        }
    }
    __syncthreads();

    f32x4 acc[2][4];
    #pragma unroll
    for (int i = 0; i < 2; ++i)
        #pragma unroll
        for (int j = 0; j < 4; ++j) acc[i][j] = (f32x4){0.f, 0.f, 0.f, 0.f};

    const ushort* wbase = WC1F + boff;
    bf16x8 bcur[4], a0c, a1c;
    #pragma unroll
    for (int ct = 0; ct < 4; ++ct)
        bcur[ct] = *(const bf16x8*)(wbase + (size_t)((w * 4 + ct) * 10) * 512);
    a0c = *(const bf16x8*)&Asub[lr * 328 + lk];
    a1c = *(const bf16x8*)&Asub[(16 + lr) * 328 + lk];

    #pragma unroll
    for (int kk = 0; kk < 10; ++kk) {
        bf16x8 bn[4], a0n, a1n;
        if (kk < 9) {
            #pragma unroll
            for (int ct = 0; ct < 4; ++ct)
                bn[ct] = *(const bf16x8*)(wbase + (size_t)((w * 4 + ct) * 10 + kk + 1) * 512);
            a0n = *(const bf16x8*)&Asub[lr * 328 + (kk + 1) * 32 + lk];
            a1n = *(const bf16x8*)&Asub[(16 + lr) * 328 + (kk + 1) * 32 + lk];
        }
        #pragma unroll
        for (int ct = 0; ct < 4; ++ct) {
            acc[0][ct] = __builtin_amdgcn_mfma_f32_16x16x32_bf16(a0c, bcur[ct], acc[0][ct], 0, 0, 0);
            acc[1][ct] = __builtin_amdgcn_mfma_f32_16x16x32_bf16(a1c, bcur[ct], acc[1][ct], 0, 0, 0);
        }
        if (kk < 9) {
            #pragma unroll
            for (int ct = 0; ct < 4; ++ct) bcur[ct] = bn[ct];
            a0c = a0n; a1c = a1n;
        }
    }

    int rbase = lkq * 4;
    #pragma unroll
    for (int ct = 0; ct < 4; ++ct) {
        int col = w * 64 + ct * 16 + lr;
        float bb = (col >= 128) ? bm1[col - 128] : 0.f;
        #pragma unroll
        for (int rt = 0; rt < 2; ++rt) {
            #pragma unroll
            for (int r = 0; r < 4; ++r) {
                int row = n0 + rt * 16 + rbase + r;
                if (row < N) {
                    float v = acc[rt][ct][r];
                    if (col < 128) Pb[(size_t)row * 128 + col] = f2bf(v);
                    else           Qb[(size_t)row * 128 + (col - 128)] = f2bf(v + bb);
                }
            }
        }
    }
}

// ---------------------------------------------------------------------------
// K_agg: segmented reduction, one wave per dst node, 2 ch/lane.
// tanh gelu (5 VALU + 2 trans); software-pipelined gathers; 32-bit offsets.
// ---------------------------------------------------------------------------
__global__ __launch_bounds__(256) void k_agg(
    const ushort* __restrict__ Pb, const ushort* __restrict__ Qb,
    const int2* __restrict__ rec, const int* __restrict__ offs,
    ushort* __restrict__ GAB, float* __restrict__ sw, int N)
{
    int n = blockIdx.x * 4 + (threadIdx.x >> 6);
    if (n >= N) return;
    int lane = threadIdx.x & 63;
    unsigned lo2 = (unsigned)(lane << 1);
    int beg = __builtin_amdgcn_readfirstlane(offs[n]);
    int end = __builtin_amdgcn_readfirstlane(offs[n + 1]);
    unsigned int qv = *(const unsigned int*)&Qb[((unsigned)n << 7) + lo2];
    float qx = bfh(qv), qy = bfl(qv);
    float a0 = 0.f, a1 = 0.f, wsum = 0.f;
    int j = beg;
    if (j + 4 <= end) {
        int2 r0 = rec[j], r1 = rec[j + 1], r2 = rec[j + 2], r3 = rec[j + 3];
        unsigned int p0 = *(const unsigned int*)&Pb[((unsigned)r0.x << 7) + lo2];
        unsigned int p1 = *(const unsigned int*)&Pb[((unsigned)r1.x << 7) + lo2];
        unsigned int p2 = *(const unsigned int*)&Pb[((unsigned)r2.x << 7) + lo2];
        unsigned int p3 = *(const unsigned int*)&Pb[((unsigned)r3.x << 7) + lo2];
        j += 4;
        while (j + 4 <= end) {
            int2 s0 = rec[j], s1 = rec[j + 1], s2 = rec[j + 2], s3 = rec[j + 3];
            unsigned int n0_ = *(const unsigned int*)&Pb[((unsigned)s0.x << 7) + lo2];
            unsigned int n1_ = *(const unsigned int*)&Pb[((unsigned)s1.x << 7) + lo2];
            unsigned int n2_ = *(const unsigned int*)&Pb[((unsigned)s2.x << 7) + lo2];
            unsigned int n3_ = *(const unsigned int*)&Pb[((unsigned)s3.x << 7) + lo2];
            float w0 = __int_as_float(r0.y), w1 = __int_as_float(r1.y);
            float w2 = __int_as_float(r2.y), w3 = __int_as_float(r3.y);
            a0 = fmaf(w0, gelu_tanh(bfh(p0) + qx), a0);
            a1 = fmaf(w0, gelu_tanh(bfl(p0) + qy), a1);
            a0 = fmaf(w1, gelu_tanh(bfh(p1) + qx), a0);
            a1 = fmaf(w1, gelu_tanh(bfl(p1) + qy), a1);
            a0 = fmaf(w2, gelu_tanh(bfh(p2) + qx), a0);
            a1 = fmaf(w2, gelu_tanh(bfl(p2) + qy), a1);
            a0 = fmaf(w3, gelu_tanh(bfh(p3) + qx), a0);
            a1 = fmaf(w3, gelu_tanh(bfl(p3) + qy), a1);
            wsum += (w0 + w1) + (w2 + w3);
            r0 = s0; r1 = s1; r2 = s2; r3 = s3;
            p0 = n0_; p1 = n1_; p2 = n2_; p3 = n3_;
            j += 4;
        }
        float w0 = __int_as_float(r0.y), w1 = __int_as_float(r1.y);
        float w2 = __int_as_float(r2.y), w3 = __int_as_float(r3.y);
        a0 = fmaf(w0, gelu_tanh(bfh(p0) + qx), a0);
        a1 = fmaf(w0, gelu_tanh(bfl(p0) + qy), a1);
        a0 = fmaf(w1, gelu_tanh(bfh(p1) + qx), a0);
        a1 = fmaf(w1, gelu_tanh(bfl(p1) + qy), a1);
        a0 = fmaf(w2, gelu_tanh(bfh(p2) + qx), a0);
        a1 = fmaf(w2, gelu_tanh(bfl(p2) + qy), a1);
        a0 = fmaf(w3, gelu_tanh(bfh(p3) + qx), a0);
        a1 = fmaf(w3, gelu_tanh(bfl(p3) + qy), a1);
        wsum += (w0 + w1) + (w2 + w3);
    }
    for (; j < end; ++j) {
        int2 r0 = rec[j];
        unsigned int p0 = *(const unsigned int*)&Pb[((unsigned)r0.x << 7) + lo2];
        float w0 = __int_as_float(r0.y);
        a0 = fmaf(w0, gelu_tanh(bfh(p0) + qx), a0);
        a1 = fmaf(w0, gelu_tanh(bfl(p0) + qy), a1);
        wsum += w0;
    }
    *(ushort2*)&GAB[((unsigned)n << 7) + lo2] = make_ushort2(f2bf(a0), f2bf(a1));
    if (lane == 0) sw[n] = wsum;
}

// ---------------------------------------------------------------------------
// K3 (MFMA): fused update MLP, 32-row blocks, fragment-major B, with
// one-iteration-ahead register prefetch in both GEMM phases.
// ---------------------------------------------------------------------------
__global__ __launch_bounds__(256) void k3_mfma(
    const float* __restrict__ s, const ushort* __restrict__ GAB, const float* __restrict__ sw,
    const ushort* __restrict__ WUCF, const float* __restrict__ BV, const float* __restrict__ bu1,
    const ushort* __restrict__ WU2F, const float* __restrict__ bu2,
    float* __restrict__ out, int N)
{
    __shared__ __align__(16) short Asub[32 * 264];
    __shared__ __align__(16) short H2[32 * 136];
    __shared__ float SWs[32];
    int tid = threadIdx.x;
    int w = tid >> 6, l = tid & 63;
    int lr = l & 15, lkq = l >> 4;
    int lk = lkq * 8;
    int boff = (lr << 5) + (lkq << 3);
    int n0 = blockIdx.x * 32;

    if (tid < 32) SWs[tid] = (n0 + tid < N) ? sw[n0 + tid] : 0.f;

    {
        int ar = tid & 31;
        int kg = (tid >> 5) * 8;
        int arow = n0 + ar; if (arow >= N) arow = N - 1;
        #pragma unroll
        for (int c = 0; c < 4; ++c) {
            int k = c * 64 + kg;
            BF8 pk;
            if (k < 128) {
                const float* asrc = s + (size_t)arow * 128 + k;
                float4 f0 = *(const float4*)asrc;
                float4 f1 = *(const float4*)(asrc + 4);
                pk.u[0] = f2bf(f0.x); pk.u[1] = f2bf(f0.y); pk.u[2] = f2bf(f0.z); pk.u[3] = f2bf(f0.w);
                pk.u[4] = f2bf(f1.x); pk.u[5] = f2bf(f1.y); pk.u[6] = f2bf(f1.z); pk.u[7] = f2bf(f1.w);
            } else {
                pk.v = *(const bf16x8*)(GAB + (size_t)arow * 128 + (k - 128));
            }
            *(bf16x8*)&Asub[ar * 264 + k] = pk.v;
        }
    }
    __syncthreads();

    // ---- Phase A: K=256, prefetched
    f32x4 acc[2][2];
    #pragma unroll
    for (int i = 0; i < 2; ++i) { acc[i][0] = (f32x4){0,0,0,0}; acc[i][1] = (f32x4){0,0,0,0}; }

    bf16x8 bcur[2], a0c, a1c;
    #pragma unroll
    for (int ct = 0; ct < 2; ++ct)
        bcur[ct] = *(const bf16x8*)(WUCF + (size_t)((w * 2 + ct) * 8) * 512 + boff);
    a0c = *(const bf16x8*)&Asub[lr * 264 + lk];
    a1c = *(const bf16x8*)&Asub[(16 + lr) * 264 + lk];

    #pragma unroll
    for (int kk = 0; kk < 8; ++kk) {
        bf16x8 bn[2], a0n, a1n;
        if (kk < 7) {
            #pragma unroll
            for (int ct = 0; ct < 2; ++ct)
                bn[ct] = *(const bf16x8*)(WUCF + (size_t)((w * 2 + ct) * 8 + kk + 1) * 512 + boff);
            a0n = *(const bf16x8*)&Asub[lr * 264 + (kk + 1) * 32 + lk];
            a1n = *(const bf16x8*)&Asub[(16 + lr) * 264 + (kk + 1) * 32 + lk];
        }
        #pragma unroll
        for (int ct = 0; ct < 2; ++ct) {
            acc[0][ct] = __builtin_amdgcn_mfma_f32_16x16x32_bf16(a0c, bcur[ct], acc[0][ct], 0, 0, 0);
            acc[1][ct] = __builtin_amdgcn_mfma_f32_16x16x32_bf16(a1c, bcur[ct], acc[1][ct], 0, 0, 0);
        }
        if (kk < 7) {
            bcur[0] = bn[0]; bcur[1] = bn[1];
            a0c = a0n; a1c = a1n;
        }
    }

    int rbase = lkq * 4;
    #pragma unroll
    for (int ct = 0; ct < 2; ++ct) {
        int col = w * 32 + ct * 16 + lr;
        float b1 = bu1[col], bv = BV[col];
        #pragma unroll
        for (int rt = 0; rt < 2; ++rt) {
            #pragma unroll
            for (int r = 0; r < 4; ++r) {
                int row16 = rt * 16 + rbase + r;
                float v = acc[rt][ct][r] + b1 + SWs[row16] * bv;
                H2[row16 * 136 + col] = (short)f2bf(gelu_fast(v));
            }
        }
    }
    __syncthreads();

    // ---- Phase B: K=128, prefetched
    f32x4 acc2[2][2];
    #pragma unroll
    for (int i = 0; i < 2; ++i) { acc2[i][0] = (f32x4){0,0,0,0}; acc2[i][1] = (f32x4){0,0,0,0}; }

    bf16x8 b2c[2], h0c, h1c;
    #pragma unroll
    for (int ct = 0; ct < 2; ++ct)
        b2c[ct] = *(const bf16x8*)(WU2F + (size_t)((w * 2 + ct) * 4) * 512 + boff);
    h0c = *(const bf16x8*)&H2[lr * 136 + lk];
    h1c = *(const bf16x8*)&H2[(16 + lr) * 136 + lk];

    #pragma unroll
    for (int kk = 0; kk < 4; ++kk) {
        bf16x8 bn[2], h0n, h1n;
        if (kk < 3) {
            #pragma unroll
            for (int ct = 0; ct < 2; ++ct)
                bn[ct] = *(const bf16x8*)(WU2F + (size_t)((w * 2 + ct) * 4 + kk + 1) * 512 + boff);
            h0n = *(const bf16x8*)&H2[lr * 136 + (kk + 1) * 32 + lk];
            h1n = *(const bf16x8*)&H2[(16 + lr) * 136 + (kk + 1) * 32 + lk];
        }
        #pragma unroll
        for (int ct = 0; ct < 2; ++ct) {
            acc2[0][ct] = __builtin_amdgcn_mfma_f32_16x16x32_bf16(h0c, b2c[ct], acc2[0][ct], 0, 0, 0);
            acc2[1][ct] = __builtin_amdgcn_mfma_f32_16x16x32_bf16(h1c, b2c[ct], acc2[1][ct], 0, 0, 0);
        }
        if (kk < 3) {
            b2c[0] = bn[0]; b2c[1] = bn[1];
            h0c = h0n; h1c = h1n;
        }
    }

    #pragma unroll
    for (int ct = 0; ct < 2; ++ct) {
        int col = w * 32 + ct * 16 + lr;
        float b2 = bu2[col];
        #pragma unroll
        for (int rt = 0; rt < 2; ++rt) {
            #pragma unroll
            for (int r = 0; r < 4; ++r) {
                int row = n0 + rt * 16 + rbase + r;
                if (row < N) out[(size_t)row * 128 + col] = acc2[rt][ct][r] + b2;
            }
        }
    }
}

// ---------------------------------------------------------------------------
extern "C" void kernel_launch(void* const* d_in, const int* in_sizes, int n_in,
                              void* d_out, int out_size, void* d_ws, size_t ws_size,
                              hipStream_t stream) {
    const float* s    = (const float*)d_in[0];
    const float* x    = (const float*)d_in[1];
    const int*   ei   = (const int*)d_in[2];
    const float* ew   = (const float*)d_in[3];
    const float* t    = (const float*)d_in[4];
    const float* Wm1  = (const float*)d_in[5];
    const float* bm1  = (const float*)d_in[6];
    const float* Wm2  = (const float*)d_in[7];
    const float* bm2  = (const float*)d_in[8];
    const float* Wu1  = (const float*)d_in[9];
    const float* bu1  = (const float*)d_in[10];
    const float* Wu2  = (const float*)d_in[11];
    const float* bu2  = (const float*)d_in[12];

    int N = in_sizes[0] / 128;
    int E = in_sizes[2] / 2;
    const int* srcI = ei;
    const int* dstI = ei + E;
    int NP = (N + CHUNK - 1) & ~(CHUNK - 1);
    int C  = NP / CHUNK;

    // workspace layout (32-bit words)
    float* ws = (float*)d_ws;
    size_t off = 0;
    ushort* Pb   = (ushort*)(ws + off); off += (size_t)N * 64;
    ushort* Qb   = (ushort*)(ws + off); off += (size_t)N * 64;
    float*  SW   = ws + off; off += ((size_t)N + 63) & ~(size_t)63;
    ushort* GAB  = (ushort*)(ws + off); off += (size_t)N * 64;
    ushort* WC1F = (ushort*)(ws + off); off += (256 * 320) / 2;
    ushort* WUCF = (ushort*)(ws + off); off += (128 * 256) / 2;
    ushort* WU2F = (ushort*)(ws + off); off += (128 * 128) / 2;
    float*  BV   = ws + off; off += 128;
    int*    DEG  = (int*)(ws + off); off += (size_t)NP;
    int*    OFFS = (int*)(ws + off); off += (size_t)NP + 64;
    off = (off + 3) & ~(size_t)3;
    int*    RANK = (int*)(ws + off); off += (size_t)E;
    int*    CSUM = (int*)(ws + off); off += 128;
    int*    CBASE= (int*)(ws + off); off += 128;
    off = (off + 3) & ~(size_t)3;
    int2*   REC  = (int2*)(ws + off); off += (size_t)E * 2;

    // zero histogram, then fused weight-prep + histogram-with-rank
    hipMemsetAsync(DEG, 0, (size_t)NP * sizeof(int), stream);
    int histBlocks = (E + 255) / 256;
    k_prep<<<512 + histBlocks, 256, 0, stream>>>(Wm1, Wu1, Wm2, bm2, Wu2, dstI, E,
                                                 WC1F, WUCF, WU2F, BV, DEG, RANK);

    // counting sort tail (no atomics in scatter)
    k_chunksum<<<C, 256, 0, stream>>>(DEG, CSUM);
    k_chunkscan<<<1, 64, 0, stream>>>(CSUM, CBASE, C, OFFS, N, E);
    k_chunkoffs<<<C, 256, 0, stream>>>(DEG, CBASE, OFFS);
    k_scatter<<<(E + 255) / 256, 256, 0, stream>>>(srcI, dstI, ew, OFFS, RANK, REC, E);

    // node precompute (MFMA)
    int nb32 = (N + 31) / 32;
    k1_mfma<<<nb32, 256, 0, stream>>>(s, x, t, WC1F, bm1, Pb, Qb, N);

    // segmented aggregation (tanh gelu, pipelined gathers)
    k_agg<<<(N + 3) / 4, 256, 0, stream>>>(Pb, Qb, REC, OFFS, GAB, SW, N);

    // update MLP (MFMA, fused, prefetched)
    k3_mfma<<<nb32, 256, 0, stream>>>(s, GAB, SW, WUCF, BV, bu1, WU2F, bu2, (float*)d_out, N);
}

// Round 18
// 167.911 us; speedup vs baseline: 1.3541x; 1.0033x over previous
//
#include <hip/hip_runtime.h>
#include <math.h>

#define NHID 128
#define CHUNK 1024

typedef __attribute__((ext_vector_type(8))) short bf16x8;
typedef __attribute__((ext_vector_type(4))) float f32x4;

union BF8 { ushort u[8]; bf16x8 v; };

__device__ __forceinline__ ushort f2bf(float f) {
    unsigned int u = __float_as_uint(f);
    u += 0x7FFFu + ((u >> 16) & 1u);      // round-to-nearest-even
    return (ushort)(u >> 16);
}
__device__ __forceinline__ float bfh(unsigned int v) { return __uint_as_float(v << 16); }
__device__ __forceinline__ float bfl(unsigned int v) { return __uint_as_float(v & 0xffff0000u); }

// Exact-erf GELU (A&S 7.1.26, max err ~1.5e-7) — k3 epilogue (6.4M evals).
__device__ __forceinline__ float gelu_fast(float x) {
    float ax = fabsf(x);
    float t  = __builtin_amdgcn_rcpf(fmaf(0.23165493f, ax, 1.0f));
    float p  = t * fmaf(t, fmaf(t, fmaf(t, fmaf(t, 1.061405429f, -1.453152027f),
                                        1.421413741f), -0.284496736f), 0.254829592f);
    float e  = __builtin_amdgcn_exp2f(-0.7213475204f * ax * ax);
    float hax = 0.5f * ax;
    return fmaf(-hax, p * e, 0.5f * x + hax);
}

// tanh-form GELU, folded to 5 VALU + 2 trans (r16: −15us on k_agg, absmax
// unchanged).  gelu ~= x - x/(1+exp2(x*(2.3022094 + 0.10294540*x^2))).
__device__ __forceinline__ float gelu_tanh(float x) {
    float x2 = x * x;
    float z  = x * fmaf(0.10294540f, x2, 2.3022094f);
    float e  = __builtin_amdgcn_exp2f(z);
    float r  = __builtin_amdgcn_rcpf(1.0f + e);
    return fmaf(-x, r, x);
}

// ---------------------------------------------------------------------------
// Fused weight prep + edge histogram WITH RANK CAPTURE (r17: -40us).
//   blocks 0-319   : WC1F   blocks 320-447 : WUCF + BV
//   blocks 448-511 : WU2F   blocks 512+    : rank[i] = atomicAdd(&deg[dst],1)
// ---------------------------------------------------------------------------
__global__ __launch_bounds__(256) void k_prep(
    const float* __restrict__ Wm1, const float* __restrict__ Wu1,
    const float* __restrict__ Wm2, const float* __restrict__ bm2,
    const float* __restrict__ Wu2, const int* __restrict__ dstI, int E,
    ushort* __restrict__ WC1F, ushort* __restrict__ WUCF,
    ushort* __restrict__ WU2F, float* __restrict__ BV,
    int* __restrict__ deg, int* __restrict__ rank)
{
    int bid = blockIdx.x, tid = threadIdx.x;
    if (bid < 320) {                      // WC1F
        int idx = bid * 256 + tid;
        int c = idx / 320, k = idx % 320;
        float v;
        if (k < 128) {
            v = (c < 128) ? Wm1[k * 128 + c] : Wm1[(128 + k) * 128 + (c - 128)];
        } else if (k < 256) {
            int kk = k - 128;
            v = (c < 128) ? Wm1[(256 + kk) * 128 + c] : -Wm1[(256 + kk) * 128 + (c - 128)];
        } else {
            int kk = k - 256;
            v = (c < 128) ? 0.0f : Wm1[(384 + kk) * 128 + (c - 128)];
        }
        int dst = ((c >> 4) * 10 + (k >> 5)) * 512 + ((c & 15) << 5) + (k & 31);
        WC1F[dst] = f2bf(v);
    } else if (bid < 448) {               // WUCF + BV
        int idx = (bid - 320) * 256 + tid;
        int c = idx >> 8, k = idx & 255;
        float v;
        if (k < 128) {
            v = Wu1[k * 128 + c];
        } else {
            int i = k - 128;
            float acc = 0.f;
            for (int j = 0; j < 128; ++j) acc += Wm2[i * 128 + j] * Wu1[(128 + j) * 128 + c];
            v = acc;
        }
        int dst = ((c >> 4) * 8 + (k >> 5)) * 512 + ((c & 15) << 5) + (k & 31);
        WUCF[dst] = f2bf(v);
        if (idx < 128) {
            float acc = 0.f;
            for (int j = 0; j < 128; ++j) acc += bm2[j] * Wu1[(128 + j) * 128 + idx];
            BV[idx] = acc;
        }
    } else if (bid < 512) {               // WU2F
        int idx = (bid - 448) * 256 + tid;
        int c = idx >> 7, k = idx & 127;
        int dst = ((c >> 4) * 4 + (k >> 5)) * 512 + ((c & 15) << 5) + (k & 31);
        WU2F[dst] = f2bf(Wu2[k * 128 + c]);
    } else {                              // histogram + rank capture
        int i = (bid - 512) * 256 + tid;
        if (i < E) rank[i] = atomicAdd(&deg[dstI[i]], 1);
    }
}

// ---------------------------------------------------------------------------
// Counting sort tail: chunksum -> chunkscan -> chunkoffs -> scatter (no atomics)
// ---------------------------------------------------------------------------
__global__ __launch_bounds__(256) void k_chunksum(const int* __restrict__ deg,
                                                  int* __restrict__ csum) {
    int c = blockIdx.x, tid = threadIdx.x;
    int4 v = ((const int4*)(deg + (size_t)c * CHUNK))[tid];
    int ts = v.x + v.y + v.z + v.w;
    #pragma unroll
    for (int d = 1; d < 64; d <<= 1) ts += __shfl_xor(ts, d);
    __shared__ int wsum[4];
    if ((tid & 63) == 0) wsum[tid >> 6] = ts;
    __syncthreads();
    if (tid == 0) csum[c] = wsum[0] + wsum[1] + wsum[2] + wsum[3];
}
__global__ void k_chunkscan(const int* __restrict__ csum, int* __restrict__ cbase,
                            int C, int* __restrict__ offs, int N, int E) {
    int lane = threadIdx.x;   // 64
    int carry = 0;
    for (int b = 0; b < C; b += 64) {
        int v = (b + lane < C) ? csum[b + lane] : 0;
        int incl = v;
        #pragma unroll
        for (int d = 1; d < 64; d <<= 1) {
            int t = __shfl_up(incl, d);
            if (lane >= d) incl += t;
        }
        if (b + lane < C) cbase[b + lane] = carry + incl - v;
        carry += __shfl(incl, 63);
    }
    if (lane == 0) offs[N] = E;
}
__global__ __launch_bounds__(256) void k_chunkoffs(const int* __restrict__ deg,
                                                   const int* __restrict__ cbase,
                                                   int* __restrict__ offs) {
    int c = blockIdx.x, tid = threadIdx.x;
    int lane = tid & 63, wid = tid >> 6;
    int4 v = ((const int4*)(deg + (size_t)c * CHUNK))[tid];
    int t0 = v.x, t1 = t0 + v.y, t2 = t1 + v.z, ts = t2 + v.w;
    int incl = ts;
    #pragma unroll
    for (int d = 1; d < 64; d <<= 1) {
        int t = __shfl_up(incl, d);
        if (lane >= d) incl += t;
    }
    __shared__ int wz[4];
    if (lane == 63) wz[wid] = incl;
    __syncthreads();
    int wbase = 0;
    for (int k2 = 0; k2 < wid; ++k2) wbase += wz[k2];
    int eb = cbase[c] + wbase + incl - ts;
    ((int4*)(offs + (size_t)c * CHUNK))[tid] = make_int4(eb, eb + t0, eb + t1, eb + t2);
}
__global__ void k_scatter(const int* __restrict__ src, const int* __restrict__ dst,
                          const float* __restrict__ w, const int* __restrict__ offs,
                          const int* __restrict__ rank, int2* __restrict__ rec, int E) {
    int i = blockIdx.x * blockDim.x + threadIdx.x;
    if (i < E) {
        int pos = offs[dst[i]] + rank[i];
        rec[pos] = make_int2(src[i], __float_as_int(w[i]));
    }
}

// ---------------------------------------------------------------------------
// K1 (MFMA): [P|Q] = [s|x|t] @ Wc1.  512 threads = 8 waves (2 row x 4 col),
// 64-row blocks: 3 blocks/CU x 8 waves = 24 waves/CU (vs 4-wave r17 variant at
// measured 28% occupancy), B-frag L2 re-reads halved (one frag serves 64 rows).
// A staged once, one barrier; B frags 1024B coalesced from fragment-major WC1F.
// ---------------------------------------------------------------------------
__global__ __launch_bounds__(512) void k1_mfma(
    const float* __restrict__ s, const float* __restrict__ x, const float* __restrict__ t,
    const ushort* __restrict__ WC1F, const float* __restrict__ bm1,
    ushort* __restrict__ Pb, ushort* __restrict__ Qb, int N)
{
    __shared__ __align__(16) short Asub[64 * 328];   // 42KB
    int tid = threadIdx.x;
    int w = tid >> 6, l = tid & 63;
    int wr = w >> 2;            // 0..1  row strip pair (rows wr*32..+31)
    int wc = w & 3;             // 0..3  col group (cols wc*64..+63)
    int lr = l & 15, lkq = l >> 4;
    int lk = lkq * 8;
    int boff = (lr << 5) + (lkq << 3);
    int n0 = blockIdx.x * 64;

    // ---- stage A tile: 512 thr, row = tid>>3, k = c*64 + (tid&7)*8, c=0..4
    {
        int ar = tid >> 3;
        int kg = (tid & 7) * 8;
        int arow = n0 + ar; if (arow >= N) arow = N - 1;
        #pragma unroll
        for (int c = 0; c < 5; ++c) {
            int k = c * 64 + kg;
            const float* asrc;
            if (k < 128)      asrc = s + (size_t)arow * 128 + k;
            else if (k < 256) asrc = x + (size_t)arow * 128 + (k - 128);
            else              asrc = t + (size_t)arow * 64 + (k - 256);
            float4 f0 = *(const float4*)asrc;
            float4 f1 = *(const float4*)(asrc + 4);
            BF8 pk;
            pk.u[0] = f2bf(f0.x); pk.u[1] = f2bf(f0.y); pk.u[2] = f2bf(f0.z); pk.u[3] = f2bf(f0.w);
            pk.u[4] = f2bf(f1.x); pk.u[5] = f2bf(f1.y); pk.u[6] = f2bf(f1.z); pk.u[7] = f2bf(f1.w);
            *(bf16x8*)&Asub[ar * 328 + k] = pk.v;
        }
    }
    __syncthreads();

    f32x4 acc[2][4];
    #pragma unroll
    for (int i = 0; i < 2; ++i)
        #pragma unroll
        for (int j = 0; j < 4; ++j) acc[i][j] = (f32x4){0.f, 0.f, 0.f, 0.f};

    int row0 = wr * 32 + lr;         // A-frag rows for strip 0
    const ushort* wbase = WC1F + boff;
    bf16x8 bcur[4], a0c, a1c;
    #pragma unroll
    for (int ct = 0; ct < 4; ++ct)
        bcur[ct] = *(const bf16x8*)(wbase + (size_t)((wc * 4 + ct) * 10) * 512);
    a0c = *(const bf16x8*)&Asub[row0 * 328 + lk];
    a1c = *(const bf16x8*)&Asub[(row0 + 16) * 328 + lk];

    #pragma unroll
    for (int kk = 0; kk < 10; ++kk) {
        bf16x8 bn[4], a0n, a1n;
        if (kk < 9) {
            #pragma unroll
            for (int ct = 0; ct < 4; ++ct)
                bn[ct] = *(const bf16x8*)(wbase + (size_t)((wc * 4 + ct) * 10 + kk + 1) * 512);
            a0n = *(const bf16x8*)&Asub[row0 * 328 + (kk + 1) * 32 + lk];
            a1n = *(const bf16x8*)&Asub[(row0 + 16) * 328 + (kk + 1) * 32 + lk];
        }
        #pragma unroll
        for (int ct = 0; ct < 4; ++ct) {
            acc[0][ct] = __builtin_amdgcn_mfma_f32_16x16x32_bf16(a0c, bcur[ct], acc[0][ct], 0, 0, 0);
            acc[1][ct] = __builtin_amdgcn_mfma_f32_16x16x32_bf16(a1c, bcur[ct], acc[1][ct], 0, 0, 0);
        }
        if (kk < 9) {
            #pragma unroll
            for (int ct = 0; ct < 4; ++ct) bcur[ct] = bn[ct];
            a0c = a0n; a1c = a1n;
        }
    }

    int rbase = lkq * 4;
    #pragma unroll
    for (int ct = 0; ct < 4; ++ct) {
        int col = wc * 64 + ct * 16 + lr;
        float bb = (col >= 128) ? bm1[col - 128] : 0.f;
        #pragma unroll
        for (int rt = 0; rt < 2; ++rt) {
            #pragma unroll
            for (int r = 0; r < 4; ++r) {
                int row = n0 + wr * 32 + rt * 16 + rbase + r;
                if (row < N) {
                    float v = acc[rt][ct][r];
                    if (col < 128) Pb[(size_t)row * 128 + col] = f2bf(v);
                    else           Qb[(size_t)row * 128 + (col - 128)] = f2bf(v + bb);
                }
            }
        }
    }
}

// ---------------------------------------------------------------------------
// K_agg: segmented reduction, one wave per dst node, 2 ch/lane.
// tanh gelu (5 VALU + 2 trans); software-pipelined gathers; 32-bit offsets.
// ---------------------------------------------------------------------------
__global__ __launch_bounds__(256) void k_agg(
    const ushort* __restrict__ Pb, const ushort* __restrict__ Qb,
    const int2* __restrict__ rec, const int* __restrict__ offs,
    ushort* __restrict__ GAB, float* __restrict__ sw, int N)
{
    int n = blockIdx.x * 4 + (threadIdx.x >> 6);
    if (n >= N) return;
    int lane = threadIdx.x & 63;
    unsigned lo2 = (unsigned)(lane << 1);
    int beg = __builtin_amdgcn_readfirstlane(offs[n]);
    int end = __builtin_amdgcn_readfirstlane(offs[n + 1]);
    unsigned int qv = *(const unsigned int*)&Qb[((unsigned)n << 7) + lo2];
    float qx = bfh(qv), qy = bfl(qv);
    float a0 = 0.f, a1 = 0.f, wsum = 0.f;
    int j = beg;
    if (j + 4 <= end) {
        int2 r0 = rec[j], r1 = rec[j + 1], r2 = rec[j + 2], r3 = rec[j + 3];
        unsigned int p0 = *(const unsigned int*)&Pb[((unsigned)r0.x << 7) + lo2];
        unsigned int p1 = *(const unsigned int*)&Pb[((unsigned)r1.x << 7) + lo2];
        unsigned int p2 = *(const unsigned int*)&Pb[((unsigned)r2.x << 7) + lo2];
        unsigned int p3 = *(const unsigned int*)&Pb[((unsigned)r3.x << 7) + lo2];
        j += 4;
        while (j + 4 <= end) {
            int2 s0 = rec[j], s1 = rec[j + 1], s2 = rec[j + 2], s3 = rec[j + 3];
            unsigned int n0_ = *(const unsigned int*)&Pb[((unsigned)s0.x << 7) + lo2];
            unsigned int n1_ = *(const unsigned int*)&Pb[((unsigned)s1.x << 7) + lo2];
            unsigned int n2_ = *(const unsigned int*)&Pb[((unsigned)s2.x << 7) + lo2];
            unsigned int n3_ = *(const unsigned int*)&Pb[((unsigned)s3.x << 7) + lo2];
            float w0 = __int_as_float(r0.y), w1 = __int_as_float(r1.y);
            float w2 = __int_as_float(r2.y), w3 = __int_as_float(r3.y);
            a0 = fmaf(w0, gelu_tanh(bfh(p0) + qx), a0);
            a1 = fmaf(w0, gelu_tanh(bfl(p0) + qy), a1);
            a0 = fmaf(w1, gelu_tanh(bfh(p1) + qx), a0);
            a1 = fmaf(w1, gelu_tanh(bfl(p1) + qy), a1);
            a0 = fmaf(w2, gelu_tanh(bfh(p2) + qx), a0);
            a1 = fmaf(w2, gelu_tanh(bfl(p2) + qy), a1);
            a0 = fmaf(w3, gelu_tanh(bfh(p3) + qx), a0);
            a1 = fmaf(w3, gelu_tanh(bfl(p3) + qy), a1);
            wsum += (w0 + w1) + (w2 + w3);
            r0 = s0; r1 = s1; r2 = s2; r3 = s3;
            p0 = n0_; p1 = n1_; p2 = n2_; p3 = n3_;
            j += 4;
        }
        float w0 = __int_as_float(r0.y), w1 = __int_as_float(r1.y);
        float w2 = __int_as_float(r2.y), w3 = __int_as_float(r3.y);
        a0 = fmaf(w0, gelu_tanh(bfh(p0) + qx), a0);
        a1 = fmaf(w0, gelu_tanh(bfl(p0) + qy), a1);
        a0 = fmaf(w1, gelu_tanh(bfh(p1) + qx), a0);
        a1 = fmaf(w1, gelu_tanh(bfl(p1) + qy), a1);
        a0 = fmaf(w2, gelu_tanh(bfh(p2) + qx), a0);
        a1 = fmaf(w2, gelu_tanh(bfl(p2) + qy), a1);
        a0 = fmaf(w3, gelu_tanh(bfh(p3) + qx), a0);
        a1 = fmaf(w3, gelu_tanh(bfl(p3) + qy), a1);
        wsum += (w0 + w1) + (w2 + w3);
    }
    for (; j < end; ++j) {
        int2 r0 = rec[j];
        unsigned int p0 = *(const unsigned int*)&Pb[((unsigned)r0.x << 7) + lo2];
        float w0 = __int_as_float(r0.y);
        a0 = fmaf(w0, gelu_tanh(bfh(p0) + qx), a0);
        a1 = fmaf(w0, gelu_tanh(bfl(p0) + qy), a1);
        wsum += w0;
    }
    *(ushort2*)&GAB[((unsigned)n << 7) + lo2] = make_ushort2(f2bf(a0), f2bf(a1));
    if (lane == 0) sw[n] = wsum;
}

// ---------------------------------------------------------------------------
// K3 (MFMA): fused update MLP, 32-row blocks, fragment-major B, with
// one-iteration-ahead register prefetch in both GEMM phases.
// ---------------------------------------------------------------------------
__global__ __launch_bounds__(256) void k3_mfma(
    const float* __restrict__ s, const ushort* __restrict__ GAB, const float* __restrict__ sw,
    const ushort* __restrict__ WUCF, const float* __restrict__ BV, const float* __restrict__ bu1,
    const ushort* __restrict__ WU2F, const float* __restrict__ bu2,
    float* __restrict__ out, int N)
{
    __shared__ __align__(16) short Asub[32 * 264];
    __shared__ __align__(16) short H2[32 * 136];
    __shared__ float SWs[32];
    int tid = threadIdx.x;
    int w = tid >> 6, l = tid & 63;
    int lr = l & 15, lkq = l >> 4;
    int lk = lkq * 8;
    int boff = (lr << 5) + (lkq << 3);
    int n0 = blockIdx.x * 32;

    if (tid < 32) SWs[tid] = (n0 + tid < N) ? sw[n0 + tid] : 0.f;

    {
        int ar = tid & 31;
        int kg = (tid >> 5) * 8;
        int arow = n0 + ar; if (arow >= N) arow = N - 1;
        #pragma unroll
        for (int c = 0; c < 4; ++c) {
            int k = c * 64 + kg;
            BF8 pk;
            if (k < 128) {
                const float* asrc = s + (size_t)arow * 128 + k;
                float4 f0 = *(const float4*)asrc;
                float4 f1 = *(const float4*)(asrc + 4);
                pk.u[0] = f2bf(f0.x); pk.u[1] = f2bf(f0.y); pk.u[2] = f2bf(f0.z); pk.u[3] = f2bf(f0.w);
                pk.u[4] = f2bf(f1.x); pk.u[5] = f2bf(f1.y); pk.u[6] = f2bf(f1.z); pk.u[7] = f2bf(f1.w);
            } else {
                pk.v = *(const bf16x8*)(GAB + (size_t)arow * 128 + (k - 128));
            }
            *(bf16x8*)&Asub[ar * 264 + k] = pk.v;
        }
    }
    __syncthreads();

    // ---- Phase A: K=256, prefetched
    f32x4 acc[2][2];
    #pragma unroll
    for (int i = 0; i < 2; ++i) { acc[i][0] = (f32x4){0,0,0,0}; acc[i][1] = (f32x4){0,0,0,0}; }

    bf16x8 bcur[2], a0c, a1c;
    #pragma unroll
    for (int ct = 0; ct < 2; ++ct)
        bcur[ct] = *(const bf16x8*)(WUCF + (size_t)((w * 2 + ct) * 8) * 512 + boff);
    a0c = *(const bf16x8*)&Asub[lr * 264 + lk];
    a1c = *(const bf16x8*)&Asub[(16 + lr) * 264 + lk];

    #pragma unroll
    for (int kk = 0; kk < 8; ++kk) {
        bf16x8 bn[2], a0n, a1n;
        if (kk < 7) {
            #pragma unroll
            for (int ct = 0; ct < 2; ++ct)
                bn[ct] = *(const bf16x8*)(WUCF + (size_t)((w * 2 + ct) * 8 + kk + 1) * 512 + boff);
            a0n = *(const bf16x8*)&Asub[lr * 264 + (kk + 1) * 32 + lk];
            a1n = *(const bf16x8*)&Asub[(16 + lr) * 264 + (kk + 1) * 32 + lk];
        }
        #pragma unroll
        for (int ct = 0; ct < 2; ++ct) {
            acc[0][ct] = __builtin_amdgcn_mfma_f32_16x16x32_bf16(a0c, bcur[ct], acc[0][ct], 0, 0, 0);
            acc[1][ct] = __builtin_amdgcn_mfma_f32_16x16x32_bf16(a1c, bcur[ct], acc[1][ct], 0, 0, 0);
        }
        if (kk < 7) {
            bcur[0] = bn[0]; bcur[1] = bn[1];
            a0c = a0n; a1c = a1n;
        }
    }

    int rbase = lkq * 4;
    #pragma unroll
    for (int ct = 0; ct < 2; ++ct) {
        int col = w * 32 + ct * 16 + lr;
        float b1 = bu1[col], bv = BV[col];
        #pragma unroll
        for (int rt = 0; rt < 2; ++rt) {
            #pragma unroll
            for (int r = 0; r < 4; ++r) {
                int row16 = rt * 16 + rbase + r;
                float v = acc[rt][ct][r] + b1 + SWs[row16] * bv;
                H2[row16 * 136 + col] = (short)f2bf(gelu_fast(v));
            }
        }
    }
    __syncthreads();

    // ---- Phase B: K=128, prefetched
    f32x4 acc2[2][2];
    #pragma unroll
    for (int i = 0; i < 2; ++i) { acc2[i][0] = (f32x4){0,0,0,0}; acc2[i][1] = (f32x4){0,0,0,0}; }

    bf16x8 b2c[2], h0c, h1c;
    #pragma unroll
    for (int ct = 0; ct < 2; ++ct)
        b2c[ct] = *(const bf16x8*)(WU2F + (size_t)((w * 2 + ct) * 4) * 512 + boff);
    h0c = *(const bf16x8*)&H2[lr * 136 + lk];
    h1c = *(const bf16x8*)&H2[(16 + lr) * 136 + lk];

    #pragma unroll
    for (int kk = 0; kk < 4; ++kk) {
        bf16x8 bn[2], h0n, h1n;
        if (kk < 3) {
            #pragma unroll
            for (int ct = 0; ct < 2; ++ct)
                bn[ct] = *(const bf16x8*)(WU2F + (size_t)((w * 2 + ct) * 4 + kk + 1) * 512 + boff);
            h0n = *(const bf16x8*)&H2[lr * 136 + (kk + 1) * 32 + lk];
            h1n = *(const bf16x8*)&H2[(16 + lr) * 136 + (kk + 1) * 32 + lk];
        }
        #pragma unroll
        for (int ct = 0; ct < 2; ++ct) {
            acc2[0][ct] = __builtin_amdgcn_mfma_f32_16x16x32_bf16(h0c, b2c[ct], acc2[0][ct], 0, 0, 0);
            acc2[1][ct] = __builtin_amdgcn_mfma_f32_16x16x32_bf16(h1c, b2c[ct], acc2[1][ct], 0, 0, 0);
        }
        if (kk < 3) {
            b2c[0] = bn[0]; b2c[1] = bn[1];
            h0c = h0n; h1c = h1n;
        }
    }

    #pragma unroll
    for (int ct = 0; ct < 2; ++ct) {
        int col = w * 32 + ct * 16 + lr;
        float b2 = bu2[col];
        #pragma unroll
        for (int rt = 0; rt < 2; ++rt) {
            #pragma unroll
            for (int r = 0; r < 4; ++r) {
                int row = n0 + rt * 16 + rbase + r;
                if (row < N) out[(size_t)row * 128 + col] = acc2[rt][ct][r] + b2;
            }
        }
    }
}

// ---------------------------------------------------------------------------
extern "C" void kernel_launch(void* const* d_in, const int* in_sizes, int n_in,
                              void* d_out, int out_size, void* d_ws, size_t ws_size,
                              hipStream_t stream) {
    const float* s    = (const float*)d_in[0];
    const float* x    = (const float*)d_in[1];
    const int*   ei   = (const int*)d_in[2];
    const float* ew   = (const float*)d_in[3];
    const float* t    = (const float*)d_in[4];
    const float* Wm1  = (const float*)d_in[5];
    const float* bm1  = (const float*)d_in[6];
    const float* Wm2  = (const float*)d_in[7];
    const float* bm2  = (const float*)d_in[8];
    const float* Wu1  = (const float*)d_in[9];
    const float* bu1  = (const float*)d_in[10];
    const float* Wu2  = (const float*)d_in[11];
    const float* bu2  = (const float*)d_in[12];

    int N = in_sizes[0] / 128;
    int E = in_sizes[2] / 2;
    const int* srcI = ei;
    const int* dstI = ei + E;
    int NP = (N + CHUNK - 1) & ~(CHUNK - 1);
    int C  = NP / CHUNK;

    // workspace layout (32-bit words)
    float* ws = (float*)d_ws;
    size_t off = 0;
    ushort* Pb   = (ushort*)(ws + off); off += (size_t)N * 64;
    ushort* Qb   = (ushort*)(ws + off); off += (size_t)N * 64;
    float*  SW   = ws + off; off += ((size_t)N + 63) & ~(size_t)63;
    ushort* GAB  = (ushort*)(ws + off); off += (size_t)N * 64;
    ushort* WC1F = (ushort*)(ws + off); off += (256 * 320) / 2;
    ushort* WUCF = (ushort*)(ws + off); off += (128 * 256) / 2;
    ushort* WU2F = (ushort*)(ws + off); off += (128 * 128) / 2;
    float*  BV   = ws + off; off += 128;
    int*    DEG  = (int*)(ws + off); off += (size_t)NP;
    int*    OFFS = (int*)(ws + off); off += (size_t)NP + 64;
    off = (off + 3) & ~(size_t)3;
    int*    RANK = (int*)(ws + off); off += (size_t)E;
    int*    CSUM = (int*)(ws + off); off += 128;
    int*    CBASE= (int*)(ws + off); off += 128;
    off = (off + 3) & ~(size_t)3;
    int2*   REC  = (int2*)(ws + off); off += (size_t)E * 2;

    // zero histogram, then fused weight-prep + histogram-with-rank
    hipMemsetAsync(DEG, 0, (size_t)NP * sizeof(int), stream);
    int histBlocks = (E + 255) / 256;
    k_prep<<<512 + histBlocks, 256, 0, stream>>>(Wm1, Wu1, Wm2, bm2, Wu2, dstI, E,
                                                 WC1F, WUCF, WU2F, BV, DEG, RANK);

    // counting sort tail (no atomics in scatter)
    k_chunksum<<<C, 256, 0, stream>>>(DEG, CSUM);
    k_chunkscan<<<1, 64, 0, stream>>>(CSUM, CBASE, C, OFFS, N, E);
    k_chunkoffs<<<C, 256, 0, stream>>>(DEG, CBASE, OFFS);
    k_scatter<<<(E + 255) / 256, 256, 0, stream>>>(srcI, dstI, ew, OFFS, RANK, REC, E);

    // node precompute (MFMA, 8-wave 64-row blocks)
    int nb64 = (N + 63) / 64;
    k1_mfma<<<nb64, 512, 0, stream>>>(s, x, t, WC1F, bm1, Pb, Qb, N);

    // segmented aggregation (tanh gelu, pipelined gathers)
    k_agg<<<(N + 3) / 4, 256, 0, stream>>>(Pb, Qb, REC, OFFS, GAB, SW, N);

    // update MLP (MFMA, fused, prefetched)
    int nb32 = (N + 31) / 32;
    k3_mfma<<<nb32, 256, 0, stream>>>(s, GAB, SW, WUCF, BV, bu1, WU2F, bu2, (float*)d_out, N);
}

// Round 19
// 162.543 us; speedup vs baseline: 1.3989x; 1.0330x over previous
//
#include <hip/hip_runtime.h>
#include <math.h>

#define NHID 128
#define CHUNK 1024

typedef __attribute__((ext_vector_type(8))) short bf16x8;
typedef __attribute__((ext_vector_type(4))) float f32x4;

union BF8 { ushort u[8]; bf16x8 v; };

__device__ __forceinline__ ushort f2bf(float f) {
    unsigned int u = __float_as_uint(f);
    u += 0x7FFFu + ((u >> 16) & 1u);      // round-to-nearest-even
    return (ushort)(u >> 16);
}
__device__ __forceinline__ float bfh(unsigned int v) { return __uint_as_float(v << 16); }
__device__ __forceinline__ float bfl(unsigned int v) { return __uint_as_float(v & 0xffff0000u); }

// Exact-erf GELU (A&S 7.1.26, max err ~1.5e-7) — k3 epilogue (6.4M evals).
__device__ __forceinline__ float gelu_fast(float x) {
    float ax = fabsf(x);
    float t  = __builtin_amdgcn_rcpf(fmaf(0.23165493f, ax, 1.0f));
    float p  = t * fmaf(t, fmaf(t, fmaf(t, fmaf(t, 1.061405429f, -1.453152027f),
                                        1.421413741f), -0.284496736f), 0.254829592f);
    float e  = __builtin_amdgcn_exp2f(-0.7213475204f * ax * ax);
    float hax = 0.5f * ax;
    return fmaf(-hax, p * e, 0.5f * x + hax);
}

// tanh-form GELU (r16: −15us on k_agg, absmax unchanged).
__device__ __forceinline__ float gelu_tanh(float x) {
    float x2 = x * x;
    float z  = x * fmaf(0.10294540f, x2, 2.3022094f);
    float e  = __builtin_amdgcn_exp2f(z);
    float r  = __builtin_amdgcn_rcpf(1.0f + e);
    return fmaf(-x, r, x);
}

// ---------------------------------------------------------------------------
// Fused weight prep + edge histogram WITH RANK CAPTURE (r17: -40us).
// ---------------------------------------------------------------------------
__global__ __launch_bounds__(256) void k_prep(
    const float* __restrict__ Wm1, const float* __restrict__ Wu1,
    const float* __restrict__ Wm2, const float* __restrict__ bm2,
    const float* __restrict__ Wu2, const int* __restrict__ dstI, int E,
    ushort* __restrict__ WC1F, ushort* __restrict__ WUCF,
    ushort* __restrict__ WU2F, float* __restrict__ BV,
    int* __restrict__ deg, int* __restrict__ rank)
{
    int bid = blockIdx.x, tid = threadIdx.x;
    if (bid < 320) {                      // WC1F
        int idx = bid * 256 + tid;
        int c = idx / 320, k = idx % 320;
        float v;
        if (k < 128) {
            v = (c < 128) ? Wm1[k * 128 + c] : Wm1[(128 + k) * 128 + (c - 128)];
        } else if (k < 256) {
            int kk = k - 128;
            v = (c < 128) ? Wm1[(256 + kk) * 128 + c] : -Wm1[(256 + kk) * 128 + (c - 128)];
        } else {
            int kk = k - 256;
            v = (c < 128) ? 0.0f : Wm1[(384 + kk) * 128 + (c - 128)];
        }
        int dst = ((c >> 4) * 10 + (k >> 5)) * 512 + ((c & 15) << 5) + (k & 31);
        WC1F[dst] = f2bf(v);
    } else if (bid < 448) {               // WUCF + BV
        int idx = (bid - 320) * 256 + tid;
        int c = idx >> 8, k = idx & 255;
        float v;
        if (k < 128) {
            v = Wu1[k * 128 + c];
        } else {
            int i = k - 128;
            float acc = 0.f;
            for (int j = 0; j < 128; ++j) acc += Wm2[i * 128 + j] * Wu1[(128 + j) * 128 + c];
            v = acc;
        }
        int dst = ((c >> 4) * 8 + (k >> 5)) * 512 + ((c & 15) << 5) + (k & 31);
        WUCF[dst] = f2bf(v);
        if (idx < 128) {
            float acc = 0.f;
            for (int j = 0; j < 128; ++j) acc += bm2[j] * Wu1[(128 + j) * 128 + idx];
            BV[idx] = acc;
        }
    } else if (bid < 512) {               // WU2F
        int idx = (bid - 448) * 256 + tid;
        int c = idx >> 7, k = idx & 127;
        int dst = ((c >> 4) * 4 + (k >> 5)) * 512 + ((c & 15) << 5) + (k & 31);
        WU2F[dst] = f2bf(Wu2[k * 128 + c]);
    } else {                              // histogram + rank capture
        int i = (bid - 512) * 256 + tid;
        if (i < E) rank[i] = atomicAdd(&deg[dstI[i]], 1);
    }
}

// ---------------------------------------------------------------------------
// Counting sort tail: chunksum -> chunkscan -> chunkoffs -> scatter (no atomics)
// ---------------------------------------------------------------------------
__global__ __launch_bounds__(256) void k_chunksum(const int* __restrict__ deg,
                                                  int* __restrict__ csum) {
    int c = blockIdx.x, tid = threadIdx.x;
    int4 v = ((const int4*)(deg + (size_t)c * CHUNK))[tid];
    int ts = v.x + v.y + v.z + v.w;
    #pragma unroll
    for (int d = 1; d < 64; d <<= 1) ts += __shfl_xor(ts, d);
    __shared__ int wsum[4];
    if ((tid & 63) == 0) wsum[tid >> 6] = ts;
    __syncthreads();
    if (tid == 0) csum[c] = wsum[0] + wsum[1] + wsum[2] + wsum[3];
}
__global__ void k_chunkscan(const int* __restrict__ csum, int* __restrict__ cbase,
                            int C, int* __restrict__ offs, int N, int E) {
    int lane = threadIdx.x;   // 64
    int carry = 0;
    for (int b = 0; b < C; b += 64) {
        int v = (b + lane < C) ? csum[b + lane] : 0;
        int incl = v;
        #pragma unroll
        for (int d = 1; d < 64; d <<= 1) {
            int t = __shfl_up(incl, d);
            if (lane >= d) incl += t;
        }
        if (b + lane < C) cbase[b + lane] = carry + incl - v;
        carry += __shfl(incl, 63);
    }
    if (lane == 0) offs[N] = E;
}
__global__ __launch_bounds__(256) void k_chunkoffs(const int* __restrict__ deg,
                                                   const int* __restrict__ cbase,
                                                   int* __restrict__ offs) {
    int c = blockIdx.x, tid = threadIdx.x;
    int lane = tid & 63, wid = tid >> 6;
    int4 v = ((const int4*)(deg + (size_t)c * CHUNK))[tid];
    int t0 = v.x, t1 = t0 + v.y, t2 = t1 + v.z, ts = t2 + v.w;
    int incl = ts;
    #pragma unroll
    for (int d = 1; d < 64; d <<= 1) {
        int t = __shfl_up(incl, d);
        if (lane >= d) incl += t;
    }
    __shared__ int wz[4];
    if (lane == 63) wz[wid] = incl;
    __syncthreads();
    int wbase = 0;
    for (int k2 = 0; k2 < wid; ++k2) wbase += wz[k2];
    int eb = cbase[c] + wbase + incl - ts;
    ((int4*)(offs + (size_t)c * CHUNK))[tid] = make_int4(eb, eb + t0, eb + t1, eb + t2);
}
__global__ void k_scatter(const int* __restrict__ src, const int* __restrict__ dst,
                          const float* __restrict__ w, const int* __restrict__ offs,
                          const int* __restrict__ rank, int2* __restrict__ rec, int E) {
    int i = blockIdx.x * blockDim.x + threadIdx.x;
    if (i < E) {
        int pos = offs[dst[i]] + rank[i];
        rec[pos] = make_int2(src[i], __float_as_int(w[i]));
    }
}

// ---------------------------------------------------------------------------
// K1 (MFMA): [P|Q] = [s|x|t] @ Wc1.  512 thr = 8 waves (2 row x 4 col),
// 64-row blocks.  Epilogue now stages outputs in LDS and stores fully
// coalesced 16B chunks (r18 counters: 2.2x write-sector amplification from
// 32B scattered ushort runs).
// ---------------------------------------------------------------------------
__global__ __launch_bounds__(512) void k1_mfma(
    const float* __restrict__ s, const float* __restrict__ x, const float* __restrict__ t,
    const ushort* __restrict__ WC1F, const float* __restrict__ bm1,
    ushort* __restrict__ Pb, ushort* __restrict__ Qb, int N)
{
    __shared__ __align__(16) short Asub[64 * 328];   // 42KB; reused for out-tile
    int tid = threadIdx.x;
    int w = tid >> 6, l = tid & 63;
    int wr = w >> 2;            // 0..1  row strip (rows wr*32..+31)
    int wc = w & 3;             // 0..3  col group (cols wc*64..+63)
    int lr = l & 15, lkq = l >> 4;
    int lk = lkq * 8;
    int boff = (lr << 5) + (lkq << 3);
    int n0 = blockIdx.x * 64;

    {
        int ar = tid >> 3;
        int kg = (tid & 7) * 8;
        int arow = n0 + ar; if (arow >= N) arow = N - 1;
        #pragma unroll
        for (int c = 0; c < 5; ++c) {
            int k = c * 64 + kg;
            const float* asrc;
            if (k < 128)      asrc = s + (size_t)arow * 128 + k;
            else if (k < 256) asrc = x + (size_t)arow * 128 + (k - 128);
            else              asrc = t + (size_t)arow * 64 + (k - 256);
            float4 f0 = *(const float4*)asrc;
            float4 f1 = *(const float4*)(asrc + 4);
            BF8 pk;
            pk.u[0] = f2bf(f0.x); pk.u[1] = f2bf(f0.y); pk.u[2] = f2bf(f0.z); pk.u[3] = f2bf(f0.w);
            pk.u[4] = f2bf(f1.x); pk.u[5] = f2bf(f1.y); pk.u[6] = f2bf(f1.z); pk.u[7] = f2bf(f1.w);
            *(bf16x8*)&Asub[ar * 328 + k] = pk.v;
        }
    }
    __syncthreads();

    f32x4 acc[2][4];
    #pragma unroll
    for (int i = 0; i < 2; ++i)
        #pragma unroll
        for (int j = 0; j < 4; ++j) acc[i][j] = (f32x4){0.f, 0.f, 0.f, 0.f};

    int row0 = wr * 32 + lr;
    const ushort* wbase = WC1F + boff;
    bf16x8 bcur[4], a0c, a1c;
    #pragma unroll
    for (int ct = 0; ct < 4; ++ct)
        bcur[ct] = *(const bf16x8*)(wbase + (size_t)((wc * 4 + ct) * 10) * 512);
    a0c = *(const bf16x8*)&Asub[row0 * 328 + lk];
    a1c = *(const bf16x8*)&Asub[(row0 + 16) * 328 + lk];

    #pragma unroll
    for (int kk = 0; kk < 10; ++kk) {
        bf16x8 bn[4], a0n, a1n;
        if (kk < 9) {
            #pragma unroll
            for (int ct = 0; ct < 4; ++ct)
                bn[ct] = *(const bf16x8*)(wbase + (size_t)((wc * 4 + ct) * 10 + kk + 1) * 512);
            a0n = *(const bf16x8*)&Asub[row0 * 328 + (kk + 1) * 32 + lk];
            a1n = *(const bf16x8*)&Asub[(row0 + 16) * 328 + (kk + 1) * 32 + lk];
        }
        #pragma unroll
        for (int ct = 0; ct < 4; ++ct) {
            acc[0][ct] = __builtin_amdgcn_mfma_f32_16x16x32_bf16(a0c, bcur[ct], acc[0][ct], 0, 0, 0);
            acc[1][ct] = __builtin_amdgcn_mfma_f32_16x16x32_bf16(a1c, bcur[ct], acc[1][ct], 0, 0, 0);
        }
        if (kk < 9) {
            #pragma unroll
            for (int ct = 0; ct < 4; ++ct) bcur[ct] = bn[ct];
            a0c = a0n; a1c = a1n;
        }
    }

    // ---- epilogue: stage [P|Q] bf16 out-tile in LDS (stride 264), then
    // fully-coalesced 16B stores (128B contiguous per 8 threads).
    __syncthreads();                      // all A-frag reads done before reuse
    int rbase = lkq * 4;
    #pragma unroll
    for (int ct = 0; ct < 4; ++ct) {
        int col = wc * 64 + ct * 16 + lr;
        float bb = (col >= 128) ? bm1[col - 128] : 0.f;
        #pragma unroll
        for (int rt = 0; rt < 2; ++rt) {
            #pragma unroll
            for (int r = 0; r < 4; ++r) {
                int lrow = wr * 32 + rt * 16 + rbase + r;
                Asub[lrow * 264 + col] = (short)f2bf(acc[rt][ct][r] + bb);
            }
        }
    }
    __syncthreads();
    {
        int lrow = tid >> 3;
        int arow = n0 + lrow;
        if (arow < N) {
            int c0 = tid & 7;
            #pragma unroll
            for (int cc = 0; cc < 4; ++cc) {
                int ch = c0 + cc * 8;            // 0..31 chunks of 8 ushorts
                bf16x8 v = *(const bf16x8*)&Asub[lrow * 264 + ch * 8];
                int col = ch * 8;
                if (col < 128) *(bf16x8*)&Pb[(size_t)arow * 128 + col] = v;
                else           *(bf16x8*)&Qb[(size_t)arow * 128 + (col - 128)] = v;
            }
        }
    }
}

// ---------------------------------------------------------------------------
// K_agg: segmented reduction, one wave per dst node, 2 ch/lane.
// tanh gelu; software-pipelined gathers; 32-bit offsets.
// ---------------------------------------------------------------------------
__global__ __launch_bounds__(256) void k_agg(
    const ushort* __restrict__ Pb, const ushort* __restrict__ Qb,
    const int2* __restrict__ rec, const int* __restrict__ offs,
    ushort* __restrict__ GAB, float* __restrict__ sw, int N)
{
    int n = blockIdx.x * 4 + (threadIdx.x >> 6);
    if (n >= N) return;
    int lane = threadIdx.x & 63;
    unsigned lo2 = (unsigned)(lane << 1);
    int beg = __builtin_amdgcn_readfirstlane(offs[n]);
    int end = __builtin_amdgcn_readfirstlane(offs[n + 1]);
    unsigned int qv = *(const unsigned int*)&Qb[((unsigned)n << 7) + lo2];
    float qx = bfh(qv), qy = bfl(qv);
    float a0 = 0.f, a1 = 0.f, wsum = 0.f;
    int j = beg;
    if (j + 4 <= end) {
        int2 r0 = rec[j], r1 = rec[j + 1], r2 = rec[j + 2], r3 = rec[j + 3];
        unsigned int p0 = *(const unsigned int*)&Pb[((unsigned)r0.x << 7) + lo2];
        unsigned int p1 = *(const unsigned int*)&Pb[((unsigned)r1.x << 7) + lo2];
        unsigned int p2 = *(const unsigned int*)&Pb[((unsigned)r2.x << 7) + lo2];
        unsigned int p3 = *(const unsigned int*)&Pb[((unsigned)r3.x << 7) + lo2];
        j += 4;
        while (j + 4 <= end) {
            int2 s0 = rec[j], s1 = rec[j + 1], s2 = rec[j + 2], s3 = rec[j + 3];
            unsigned int n0_ = *(const unsigned int*)&Pb[((unsigned)s0.x << 7) + lo2];
            unsigned int n1_ = *(const unsigned int*)&Pb[((unsigned)s1.x << 7) + lo2];
            unsigned int n2_ = *(const unsigned int*)&Pb[((unsigned)s2.x << 7) + lo2];
            unsigned int n3_ = *(const unsigned int*)&Pb[((unsigned)s3.x << 7) + lo2];
            float w0 = __int_as_float(r0.y), w1 = __int_as_float(r1.y);
            float w2 = __int_as_float(r2.y), w3 = __int_as_float(r3.y);
            a0 = fmaf(w0, gelu_tanh(bfh(p0) + qx), a0);
            a1 = fmaf(w0, gelu_tanh(bfl(p0) + qy), a1);
            a0 = fmaf(w1, gelu_tanh(bfh(p1) + qx), a0);
            a1 = fmaf(w1, gelu_tanh(bfl(p1) + qy), a1);
            a0 = fmaf(w2, gelu_tanh(bfh(p2) + qx), a0);
            a1 = fmaf(w2, gelu_tanh(bfl(p2) + qy), a1);
            a0 = fmaf(w3, gelu_tanh(bfh(p3) + qx), a0);
            a1 = fmaf(w3, gelu_tanh(bfl(p3) + qy), a1);
            wsum += (w0 + w1) + (w2 + w3);
            r0 = s0; r1 = s1; r2 = s2; r3 = s3;
            p0 = n0_; p1 = n1_; p2 = n2_; p3 = n3_;
            j += 4;
        }
        float w0 = __int_as_float(r0.y), w1 = __int_as_float(r1.y);
        float w2 = __int_as_float(r2.y), w3 = __int_as_float(r3.y);
        a0 = fmaf(w0, gelu_tanh(bfh(p0) + qx), a0);
        a1 = fmaf(w0, gelu_tanh(bfl(p0) + qy), a1);
        a0 = fmaf(w1, gelu_tanh(bfh(p1) + qx), a0);
        a1 = fmaf(w1, gelu_tanh(bfl(p1) + qy), a1);
        a0 = fmaf(w2, gelu_tanh(bfh(p2) + qx), a0);
        a1 = fmaf(w2, gelu_tanh(bfl(p2) + qy), a1);
        a0 = fmaf(w3, gelu_tanh(bfh(p3) + qx), a0);
        a1 = fmaf(w3, gelu_tanh(bfl(p3) + qy), a1);
        wsum += (w0 + w1) + (w2 + w3);
    }
    for (; j < end; ++j) {
        int2 r0 = rec[j];
        unsigned int p0 = *(const unsigned int*)&Pb[((unsigned)r0.x << 7) + lo2];
        float w0 = __int_as_float(r0.y);
        a0 = fmaf(w0, gelu_tanh(bfh(p0) + qx), a0);
        a1 = fmaf(w0, gelu_tanh(bfl(p0) + qy), a1);
        wsum += w0;
    }
    *(ushort2*)&GAB[((unsigned)n << 7) + lo2] = make_ushort2(f2bf(a0), f2bf(a1));
    if (lane == 0) sw[n] = wsum;
}

// ---------------------------------------------------------------------------
// K3 (MFMA): fused update MLP, 32-row blocks, fragment-major B, prefetched.
// ---------------------------------------------------------------------------
__global__ __launch_bounds__(256) void k3_mfma(
    const float* __restrict__ s, const ushort* __restrict__ GAB, const float* __restrict__ sw,
    const ushort* __restrict__ WUCF, const float* __restrict__ BV, const float* __restrict__ bu1,
    const ushort* __restrict__ WU2F, const float* __restrict__ bu2,
    float* __restrict__ out, int N)
{
    __shared__ __align__(16) short Asub[32 * 264];
    __shared__ __align__(16) short H2[32 * 136];
    __shared__ float SWs[32];
    int tid = threadIdx.x;
    int w = tid >> 6, l = tid & 63;
    int lr = l & 15, lkq = l >> 4;
    int lk = lkq * 8;
    int boff = (lr << 5) + (lkq << 3);
    int n0 = blockIdx.x * 32;

    if (tid < 32) SWs[tid] = (n0 + tid < N) ? sw[n0 + tid] : 0.f;

    {
        int ar = tid & 31;
        int kg = (tid >> 5) * 8;
        int arow = n0 + ar; if (arow >= N) arow = N - 1;
        #pragma unroll
        for (int c = 0; c < 4; ++c) {
            int k = c * 64 + kg;
            BF8 pk;
            if (k < 128) {
                const float* asrc = s + (size_t)arow * 128 + k;
                float4 f0 = *(const float4*)asrc;
                float4 f1 = *(const float4*)(asrc + 4);
                pk.u[0] = f2bf(f0.x); pk.u[1] = f2bf(f0.y); pk.u[2] = f2bf(f0.z); pk.u[3] = f2bf(f0.w);
                pk.u[4] = f2bf(f1.x); pk.u[5] = f2bf(f1.y); pk.u[6] = f2bf(f1.z); pk.u[7] = f2bf(f1.w);
            } else {
                pk.v = *(const bf16x8*)(GAB + (size_t)arow * 128 + (k - 128));
            }
            *(bf16x8*)&Asub[ar * 264 + k] = pk.v;
        }
    }
    __syncthreads();

    f32x4 acc[2][2];
    #pragma unroll
    for (int i = 0; i < 2; ++i) { acc[i][0] = (f32x4){0,0,0,0}; acc[i][1] = (f32x4){0,0,0,0}; }

    bf16x8 bcur[2], a0c, a1c;
    #pragma unroll
    for (int ct = 0; ct < 2; ++ct)
        bcur[ct] = *(const bf16x8*)(WUCF + (size_t)((w * 2 + ct) * 8) * 512 + boff);
    a0c = *(const bf16x8*)&Asub[lr * 264 + lk];
    a1c = *(const bf16x8*)&Asub[(16 + lr) * 264 + lk];

    #pragma unroll
    for (int kk = 0; kk < 8; ++kk) {
        bf16x8 bn[2], a0n, a1n;
        if (kk < 7) {
            #pragma unroll
            for (int ct = 0; ct < 2; ++ct)
                bn[ct] = *(const bf16x8*)(WUCF + (size_t)((w * 2 + ct) * 8 + kk + 1) * 512 + boff);
            a0n = *(const bf16x8*)&Asub[lr * 264 + (kk + 1) * 32 + lk];
            a1n = *(const bf16x8*)&Asub[(16 + lr) * 264 + (kk + 1) * 32 + lk];
        }
        #pragma unroll
        for (int ct = 0; ct < 2; ++ct) {
            acc[0][ct] = __builtin_amdgcn_mfma_f32_16x16x32_bf16(a0c, bcur[ct], acc[0][ct], 0, 0, 0);
            acc[1][ct] = __builtin_amdgcn_mfma_f32_16x16x32_bf16(a1c, bcur[ct], acc[1][ct], 0, 0, 0);
        }
        if (kk < 7) {
            bcur[0] = bn[0]; bcur[1] = bn[1];
            a0c = a0n; a1c = a1n;
        }
    }

    int rbase = lkq * 4;
    #pragma unroll
    for (int ct = 0; ct < 2; ++ct) {
        int col = w * 32 + ct * 16 + lr;
        float b1 = bu1[col], bv = BV[col];
        #pragma unroll
        for (int rt = 0; rt < 2; ++rt) {
            #pragma unroll
            for (int r = 0; r < 4; ++r) {
                int row16 = rt * 16 + rbase + r;
                float v = acc[rt][ct][r] + b1 + SWs[row16] * bv;
                H2[row16 * 136 + col] = (short)f2bf(gelu_fast(v));
            }
        }
    }
    __syncthreads();

    f32x4 acc2[2][2];
    #pragma unroll
    for (int i = 0; i < 2; ++i) { acc2[i][0] = (f32x4){0,0,0,0}; acc2[i][1] = (f32x4){0,0,0,0}; }

    bf16x8 b2c[2], h0c, h1c;
    #pragma unroll
    for (int ct = 0; ct < 2; ++ct)
        b2c[ct] = *(const bf16x8*)(WU2F + (size_t)((w * 2 + ct) * 4) * 512 + boff);
    h0c = *(const bf16x8*)&H2[lr * 136 + lk];
    h1c = *(const bf16x8*)&H2[(16 + lr) * 136 + lk];

    #pragma unroll
    for (int kk = 0; kk < 4; ++kk) {
        bf16x8 bn[2], h0n, h1n;
        if (kk < 3) {
            #pragma unroll
            for (int ct = 0; ct < 2; ++ct)
                bn[ct] = *(const bf16x8*)(WU2F + (size_t)((w * 2 + ct) * 4 + kk + 1) * 512 + boff);
            h0n = *(const bf16x8*)&H2[lr * 136 + (kk + 1) * 32 + lk];
            h1n = *(const bf16x8*)&H2[(16 + lr) * 136 + (kk + 1) * 32 + lk];
        }
        #pragma unroll
        for (int ct = 0; ct < 2; ++ct) {
            acc2[0][ct] = __builtin_amdgcn_mfma_f32_16x16x32_bf16(h0c, b2c[ct], acc2[0][ct], 0, 0, 0);
            acc2[1][ct] = __builtin_amdgcn_mfma_f32_16x16x32_bf16(h1c, b2c[ct], acc2[1][ct], 0, 0, 0);
        }
        if (kk < 3) {
            b2c[0] = bn[0]; b2c[1] = bn[1];
            h0c = h0n; h1c = h1n;
        }
    }

    #pragma unroll
    for (int ct = 0; ct < 2; ++ct) {
        int col = w * 32 + ct * 16 + lr;
        float b2 = bu2[col];
        #pragma unroll
        for (int rt = 0; rt < 2; ++rt) {
            #pragma unroll
            for (int r = 0; r < 4; ++r) {
                int row = n0 + rt * 16 + rbase + r;
                if (row < N) out[(size_t)row * 128 + col] = acc2[rt][ct][r] + b2;
            }
        }
    }
}

// ---------------------------------------------------------------------------
extern "C" void kernel_launch(void* const* d_in, const int* in_sizes, int n_in,
                              void* d_out, int out_size, void* d_ws, size_t ws_size,
                              hipStream_t stream) {
    const float* s    = (const float*)d_in[0];
    const float* x    = (const float*)d_in[1];
    const int*   ei   = (const int*)d_in[2];
    const float* ew   = (const float*)d_in[3];
    const float* t    = (const float*)d_in[4];
    const float* Wm1  = (const float*)d_in[5];
    const float* bm1  = (const float*)d_in[6];
    const float* Wm2  = (const float*)d_in[7];
    const float* bm2  = (const float*)d_in[8];
    const float* Wu1  = (const float*)d_in[9];
    const float* bu1  = (const float*)d_in[10];
    const float* Wu2  = (const float*)d_in[11];
    const float* bu2  = (const float*)d_in[12];

    int N = in_sizes[0] / 128;
    int E = in_sizes[2] / 2;
    const int* srcI = ei;
    const int* dstI = ei + E;
    int NP = (N + CHUNK - 1) & ~(CHUNK - 1);
    int C  = NP / CHUNK;

    // workspace layout (32-bit words)
    float* ws = (float*)d_ws;
    size_t off = 0;
    ushort* Pb   = (ushort*)(ws + off); off += (size_t)N * 64;
    ushort* Qb   = (ushort*)(ws + off); off += (size_t)N * 64;
    float*  SW   = ws + off; off += ((size_t)N + 63) & ~(size_t)63;
    ushort* GAB  = (ushort*)(ws + off); off += (size_t)N * 64;
    ushort* WC1F = (ushort*)(ws + off); off += (256 * 320) / 2;
    ushort* WUCF = (ushort*)(ws + off); off += (128 * 256) / 2;
    ushort* WU2F = (ushort*)(ws + off); off += (128 * 128) / 2;
    float*  BV   = ws + off; off += 128;
    int*    DEG  = (int*)(ws + off); off += (size_t)NP;
    int*    OFFS = (int*)(ws + off); off += (size_t)NP + 64;
    off = (off + 3) & ~(size_t)3;
    int*    RANK = (int*)(ws + off); off += (size_t)E;
    int*    CSUM = (int*)(ws + off); off += 128;
    int*    CBASE= (int*)(ws + off); off += 128;
    off = (off + 3) & ~(size_t)3;
    int2*   REC  = (int2*)(ws + off); off += (size_t)E * 2;

    // zero histogram, then fused weight-prep + histogram-with-rank
    hipMemsetAsync(DEG, 0, (size_t)NP * sizeof(int), stream);
    int histBlocks = (E + 255) / 256;
    k_prep<<<512 + histBlocks, 256, 0, stream>>>(Wm1, Wu1, Wm2, bm2, Wu2, dstI, E,
                                                 WC1F, WUCF, WU2F, BV, DEG, RANK);

    // counting sort tail (no atomics in scatter)
    k_chunksum<<<C, 256, 0, stream>>>(DEG, CSUM);
    k_chunkscan<<<1, 64, 0, stream>>>(CSUM, CBASE, C, OFFS, N, E);
    k_chunkoffs<<<C, 256, 0, stream>>>(DEG, CBASE, OFFS);
    k_scatter<<<(E + 255) / 256, 256, 0, stream>>>(srcI, dstI, ew, OFFS, RANK, REC, E);

    // node precompute (MFMA, coalesced epilogue)
    int nb64 = (N + 63) / 64;
    k1_mfma<<<nb64, 512, 0, stream>>>(s, x, t, WC1F, bm1, Pb, Qb, N);

    // segmented aggregation (tanh gelu, pipelined gathers)
    k_agg<<<(N + 3) / 4, 256, 0, stream>>>(Pb, Qb, REC, OFFS, GAB, SW, N);

    // update MLP (MFMA, fused, prefetched)
    int nb32 = (N + 31) / 32;
    k3_mfma<<<nb32, 256, 0, stream>>>(s, GAB, SW, WUCF, BV, bu1, WU2F, bu2, (float*)d_out, N);
}

// Round 20
// 159.646 us; speedup vs baseline: 1.4243x; 1.0181x over previous
//
#include <hip/hip_runtime.h>
#include <math.h>

#define NHID 128
#define CHUNK 1024

typedef __attribute__((ext_vector_type(8))) short bf16x8;
typedef __attribute__((ext_vector_type(4))) float f32x4;

union BF8 { ushort u[8]; bf16x8 v; };

__device__ __forceinline__ ushort f2bf(float f) {
    unsigned int u = __float_as_uint(f);
    u += 0x7FFFu + ((u >> 16) & 1u);      // round-to-nearest-even
    return (ushort)(u >> 16);
}
__device__ __forceinline__ float bfh(unsigned int v) { return __uint_as_float(v << 16); }
__device__ __forceinline__ float bfl(unsigned int v) { return __uint_as_float(v & 0xffff0000u); }

// Exact-erf GELU (A&S 7.1.26, max err ~1.5e-7) — k3 epilogue (6.4M evals).
__device__ __forceinline__ float gelu_fast(float x) {
    float ax = fabsf(x);
    float t  = __builtin_amdgcn_rcpf(fmaf(0.23165493f, ax, 1.0f));
    float p  = t * fmaf(t, fmaf(t, fmaf(t, fmaf(t, 1.061405429f, -1.453152027f),
                                        1.421413741f), -0.284496736f), 0.254829592f);
    float e  = __builtin_amdgcn_exp2f(-0.7213475204f * ax * ax);
    float hax = 0.5f * ax;
    return fmaf(-hax, p * e, 0.5f * x + hax);
}

// tanh-form GELU (r16: −15us on k_agg, absmax unchanged).
__device__ __forceinline__ float gelu_tanh(float x) {
    float x2 = x * x;
    float z  = x * fmaf(0.10294540f, x2, 2.3022094f);
    float e  = __builtin_amdgcn_exp2f(z);
    float r  = __builtin_amdgcn_rcpf(1.0f + e);
    return fmaf(-x, r, x);
}

// ---------------------------------------------------------------------------
// Fused weight prep + edge histogram WITH RANK CAPTURE (r17: -40us).
// ---------------------------------------------------------------------------
__global__ __launch_bounds__(256) void k_prep(
    const float* __restrict__ Wm1, const float* __restrict__ Wu1,
    const float* __restrict__ Wm2, const float* __restrict__ bm2,
    const float* __restrict__ Wu2, const int* __restrict__ dstI, int E,
    ushort* __restrict__ WC1F, ushort* __restrict__ WUCF,
    ushort* __restrict__ WU2F, float* __restrict__ BV,
    int* __restrict__ deg, int* __restrict__ rank)
{
    int bid = blockIdx.x, tid = threadIdx.x;
    if (bid < 320) {                      // WC1F
        int idx = bid * 256 + tid;
        int c = idx / 320, k = idx % 320;
        float v;
        if (k < 128) {
            v = (c < 128) ? Wm1[k * 128 + c] : Wm1[(128 + k) * 128 + (c - 128)];
        } else if (k < 256) {
            int kk = k - 128;
            v = (c < 128) ? Wm1[(256 + kk) * 128 + c] : -Wm1[(256 + kk) * 128 + (c - 128)];
        } else {
            int kk = k - 256;
            v = (c < 128) ? 0.0f : Wm1[(384 + kk) * 128 + (c - 128)];
        }
        int dst = ((c >> 4) * 10 + (k >> 5)) * 512 + ((c & 15) << 5) + (k & 31);
        WC1F[dst] = f2bf(v);
    } else if (bid < 448) {               // WUCF + BV
        int idx = (bid - 320) * 256 + tid;
        int c = idx >> 8, k = idx & 255;
        float v;
        if (k < 128) {
            v = Wu1[k * 128 + c];
        } else {
            int i = k - 128;
            float acc = 0.f;
            for (int j = 0; j < 128; ++j) acc += Wm2[i * 128 + j] * Wu1[(128 + j) * 128 + c];
            v = acc;
        }
        int dst = ((c >> 4) * 8 + (k >> 5)) * 512 + ((c & 15) << 5) + (k & 31);
        WUCF[dst] = f2bf(v);
        if (idx < 128) {
            float acc = 0.f;
            for (int j = 0; j < 128; ++j) acc += bm2[j] * Wu1[(128 + j) * 128 + idx];
            BV[idx] = acc;
        }
    } else if (bid < 512) {               // WU2F
        int idx = (bid - 448) * 256 + tid;
        int c = idx >> 7, k = idx & 127;
        int dst = ((c >> 4) * 4 + (k >> 5)) * 512 + ((c & 15) << 5) + (k & 31);
        WU2F[dst] = f2bf(Wu2[k * 128 + c]);
    } else {                              // histogram + rank capture
        int i = (bid - 512) * 256 + tid;
        if (i < E) rank[i] = atomicAdd(&deg[dstI[i]], 1);
    }
}

// ---------------------------------------------------------------------------
// Counting sort tail: chunksum -> chunkscan -> chunkoffs -> scatter (no atomics)
// ---------------------------------------------------------------------------
__global__ __launch_bounds__(256) void k_chunksum(const int* __restrict__ deg,
                                                  int* __restrict__ csum) {
    int c = blockIdx.x, tid = threadIdx.x;
    int4 v = ((const int4*)(deg + (size_t)c * CHUNK))[tid];
    int ts = v.x + v.y + v.z + v.w;
    #pragma unroll
    for (int d = 1; d < 64; d <<= 1) ts += __shfl_xor(ts, d);
    __shared__ int wsum[4];
    if ((tid & 63) == 0) wsum[tid >> 6] = ts;
    __syncthreads();
    if (tid == 0) csum[c] = wsum[0] + wsum[1] + wsum[2] + wsum[3];
}
__global__ void k_chunkscan(const int* __restrict__ csum, int* __restrict__ cbase,
                            int C, int* __restrict__ offs, int N, int E) {
    int lane = threadIdx.x;   // 64
    int carry = 0;
    for (int b = 0; b < C; b += 64) {
        int v = (b + lane < C) ? csum[b + lane] : 0;
        int incl = v;
        #pragma unroll
        for (int d = 1; d < 64; d <<= 1) {
            int t = __shfl_up(incl, d);
            if (lane >= d) incl += t;
        }
        if (b + lane < C) cbase[b + lane] = carry + incl - v;
        carry += __shfl(incl, 63);
    }
    if (lane == 0) offs[N] = E;
}
__global__ __launch_bounds__(256) void k_chunkoffs(const int* __restrict__ deg,
                                                   const int* __restrict__ cbase,
                                                   int* __restrict__ offs) {
    int c = blockIdx.x, tid = threadIdx.x;
    int lane = tid & 63, wid = tid >> 6;
    int4 v = ((const int4*)(deg + (size_t)c * CHUNK))[tid];
    int t0 = v.x, t1 = t0 + v.y, t2 = t1 + v.z, ts = t2 + v.w;
    int incl = ts;
    #pragma unroll
    for (int d = 1; d < 64; d <<= 1) {
        int t = __shfl_up(incl, d);
        if (lane >= d) incl += t;
    }
    __shared__ int wz[4];
    if (lane == 63) wz[wid] = incl;
    __syncthreads();
    int wbase = 0;
    for (int k2 = 0; k2 < wid; ++k2) wbase += wz[k2];
    int eb = cbase[c] + wbase + incl - ts;
    ((int4*)(offs + (size_t)c * CHUNK))[tid] = make_int4(eb, eb + t0, eb + t1, eb + t2);
}
__global__ void k_scatter(const int* __restrict__ src, const int* __restrict__ dst,
                          const float* __restrict__ w, const int* __restrict__ offs,
                          const int* __restrict__ rank, int2* __restrict__ rec, int E) {
    int i = blockIdx.x * blockDim.x + threadIdx.x;
    if (i < E) {
        int pos = offs[dst[i]] + rank[i];
        rec[pos] = make_int2(src[i], __float_as_int(w[i]));
    }
}

// ---------------------------------------------------------------------------
// K1 (MFMA): [P|Q] = [s|x|t] @ Wc1.  512 thr = 8 waves, 64-row blocks,
// LDS-staged coalesced epilogue (r19: -10us; write-sector amp fixed).
// ---------------------------------------------------------------------------
__global__ __launch_bounds__(512) void k1_mfma(
    const float* __restrict__ s, const float* __restrict__ x, const float* __restrict__ t,
    const ushort* __restrict__ WC1F, const float* __restrict__ bm1,
    ushort* __restrict__ Pb, ushort* __restrict__ Qb, int N)
{
    __shared__ __align__(16) short Asub[64 * 328];   // 42KB; reused for out-tile
    int tid = threadIdx.x;
    int w = tid >> 6, l = tid & 63;
    int wr = w >> 2;
    int wc = w & 3;
    int lr = l & 15, lkq = l >> 4;
    int lk = lkq * 8;
    int boff = (lr << 5) + (lkq << 3);
    int n0 = blockIdx.x * 64;

    {
        int ar = tid >> 3;
        int kg = (tid & 7) * 8;
        int arow = n0 + ar; if (arow >= N) arow = N - 1;
        #pragma unroll
        for (int c = 0; c < 5; ++c) {
            int k = c * 64 + kg;
            const float* asrc;
            if (k < 128)      asrc = s + (size_t)arow * 128 + k;
            else if (k < 256) asrc = x + (size_t)arow * 128 + (k - 128);
            else              asrc = t + (size_t)arow * 64 + (k - 256);
            float4 f0 = *(const float4*)asrc;
            float4 f1 = *(const float4*)(asrc + 4);
            BF8 pk;
            pk.u[0] = f2bf(f0.x); pk.u[1] = f2bf(f0.y); pk.u[2] = f2bf(f0.z); pk.u[3] = f2bf(f0.w);
            pk.u[4] = f2bf(f1.x); pk.u[5] = f2bf(f1.y); pk.u[6] = f2bf(f1.z); pk.u[7] = f2bf(f1.w);
            *(bf16x8*)&Asub[ar * 328 + k] = pk.v;
        }
    }
    __syncthreads();

    f32x4 acc[2][4];
    #pragma unroll
    for (int i = 0; i < 2; ++i)
        #pragma unroll
        for (int j = 0; j < 4; ++j) acc[i][j] = (f32x4){0.f, 0.f, 0.f, 0.f};

    int row0 = wr * 32 + lr;
    const ushort* wbase = WC1F + boff;
    bf16x8 bcur[4], a0c, a1c;
    #pragma unroll
    for (int ct = 0; ct < 4; ++ct)
        bcur[ct] = *(const bf16x8*)(wbase + (size_t)((wc * 4 + ct) * 10) * 512);
    a0c = *(const bf16x8*)&Asub[row0 * 328 + lk];
    a1c = *(const bf16x8*)&Asub[(row0 + 16) * 328 + lk];

    #pragma unroll
    for (int kk = 0; kk < 10; ++kk) {
        bf16x8 bn[4], a0n, a1n;
        if (kk < 9) {
            #pragma unroll
            for (int ct = 0; ct < 4; ++ct)
                bn[ct] = *(const bf16x8*)(wbase + (size_t)((wc * 4 + ct) * 10 + kk + 1) * 512);
            a0n = *(const bf16x8*)&Asub[row0 * 328 + (kk + 1) * 32 + lk];
            a1n = *(const bf16x8*)&Asub[(row0 + 16) * 328 + (kk + 1) * 32 + lk];
        }
        #pragma unroll
        for (int ct = 0; ct < 4; ++ct) {
            acc[0][ct] = __builtin_amdgcn_mfma_f32_16x16x32_bf16(a0c, bcur[ct], acc[0][ct], 0, 0, 0);
            acc[1][ct] = __builtin_amdgcn_mfma_f32_16x16x32_bf16(a1c, bcur[ct], acc[1][ct], 0, 0, 0);
        }
        if (kk < 9) {
            #pragma unroll
            for (int ct = 0; ct < 4; ++ct) bcur[ct] = bn[ct];
            a0c = a0n; a1c = a1n;
        }
    }

    __syncthreads();
    int rbase = lkq * 4;
    #pragma unroll
    for (int ct = 0; ct < 4; ++ct) {
        int col = wc * 64 + ct * 16 + lr;
        float bb = (col >= 128) ? bm1[col - 128] : 0.f;
        #pragma unroll
        for (int rt = 0; rt < 2; ++rt) {
            #pragma unroll
            for (int r = 0; r < 4; ++r) {
                int lrow = wr * 32 + rt * 16 + rbase + r;
                Asub[lrow * 264 + col] = (short)f2bf(acc[rt][ct][r] + bb);
            }
        }
    }
    __syncthreads();
    {
        int lrow = tid >> 3;
        int arow = n0 + lrow;
        if (arow < N) {
            int c0 = tid & 7;
            #pragma unroll
            for (int cc = 0; cc < 4; ++cc) {
                int ch = c0 + cc * 8;
                bf16x8 v = *(const bf16x8*)&Asub[lrow * 264 + ch * 8];
                int col = ch * 8;
                if (col < 128) *(bf16x8*)&Pb[(size_t)arow * 128 + col] = v;
                else           *(bf16x8*)&Qb[(size_t)arow * 128 + (col - 128)] = v;
            }
        }
    }
}

// ---------------------------------------------------------------------------
// K_agg: segmented reduction, one wave per dst node, 2 ch/lane.
// tanh gelu; 8-deep software-pipelined gathers (VGPR=16 headroom, r19).
// ---------------------------------------------------------------------------
__global__ __launch_bounds__(256) void k_agg(
    const ushort* __restrict__ Pb, const ushort* __restrict__ Qb,
    const int2* __restrict__ rec, const int* __restrict__ offs,
    ushort* __restrict__ GAB, float* __restrict__ sw, int N)
{
    int n = blockIdx.x * 4 + (threadIdx.x >> 6);
    if (n >= N) return;
    int lane = threadIdx.x & 63;
    unsigned lo2 = (unsigned)(lane << 1);
    int beg = __builtin_amdgcn_readfirstlane(offs[n]);
    int end = __builtin_amdgcn_readfirstlane(offs[n + 1]);
    unsigned int qv = *(const unsigned int*)&Qb[((unsigned)n << 7) + lo2];
    float qx = bfh(qv), qy = bfl(qv);
    float a0 = 0.f, a1 = 0.f, wsum = 0.f;

    #define LOADB(rr, pp, idx)                                            \
        rr = rec[idx];                                                    \
        pp = *(const unsigned int*)&Pb[((unsigned)rr.x << 7) + lo2];
    #define ACCB(rr, pp)                                                  \
        {                                                                 \
            float wv = __int_as_float(rr.y);                              \
            a0 = fmaf(wv, gelu_tanh(bfh(pp) + qx), a0);                   \
            a1 = fmaf(wv, gelu_tanh(bfl(pp) + qy), a1);                   \
            wsum += wv;                                                   \
        }

    int j = beg;
    if (j + 8 <= end) {
        int2 r0, r1, r2, r3, r4, r5, r6, r7;
        unsigned int p0, p1, p2, p3, p4, p5, p6, p7;
        LOADB(r0, p0, j + 0) LOADB(r1, p1, j + 1) LOADB(r2, p2, j + 2) LOADB(r3, p3, j + 3)
        LOADB(r4, p4, j + 4) LOADB(r5, p5, j + 5) LOADB(r6, p6, j + 6) LOADB(r7, p7, j + 7)
        j += 8;
        while (j + 8 <= end) {
            int2 s0, s1, s2, s3, s4, s5, s6, s7;
            unsigned int q0, q1, q2, q3, q4, q5, q6, q7;
            LOADB(s0, q0, j + 0) LOADB(s1, q1, j + 1) LOADB(s2, q2, j + 2) LOADB(s3, q3, j + 3)
            LOADB(s4, q4, j + 4) LOADB(s5, q5, j + 5) LOADB(s6, q6, j + 6) LOADB(s7, q7, j + 7)
            ACCB(r0, p0) ACCB(r1, p1) ACCB(r2, p2) ACCB(r3, p3)
            ACCB(r4, p4) ACCB(r5, p5) ACCB(r6, p6) ACCB(r7, p7)
            r0 = s0; p0 = q0; r1 = s1; p1 = q1; r2 = s2; p2 = q2; r3 = s3; p3 = q3;
            r4 = s4; p4 = q4; r5 = s5; p5 = q5; r6 = s6; p6 = q6; r7 = s7; p7 = q7;
            j += 8;
        }
        ACCB(r0, p0) ACCB(r1, p1) ACCB(r2, p2) ACCB(r3, p3)
        ACCB(r4, p4) ACCB(r5, p5) ACCB(r6, p6) ACCB(r7, p7)
    }
    for (; j < end; ++j) {
        int2 r0; unsigned int p0;
        LOADB(r0, p0, j)
        ACCB(r0, p0)
    }
    #undef LOADB
    #undef ACCB
    *(ushort2*)&GAB[((unsigned)n << 7) + lo2] = make_ushort2(f2bf(a0), f2bf(a1));
    if (lane == 0) sw[n] = wsum;
}

// ---------------------------------------------------------------------------
// K3 (MFMA): fused update MLP, ported to the k1 r18/r19 structure:
// 512 thr = 8 waves (2 row-strips x 4 col-groups), 64-row blocks, prefetched,
// LDS-staged coalesced fp32 epilogue (Asub reused as float out-tile).
// ---------------------------------------------------------------------------
__global__ __launch_bounds__(512) void k3_mfma(
    const float* __restrict__ s, const ushort* __restrict__ GAB, const float* __restrict__ sw,
    const ushort* __restrict__ WUCF, const float* __restrict__ BV, const float* __restrict__ bu1,
    const ushort* __restrict__ WU2F, const float* __restrict__ bu2,
    float* __restrict__ out, int N)
{
    __shared__ __align__(16) short Asub[64 * 264];   // 33792B; reused as 64x132 floats
    __shared__ __align__(16) short H2[64 * 136];     // 17408B
    __shared__ float SWs[64];
    int tid = threadIdx.x;
    int w = tid >> 6, l = tid & 63;
    int wr = w >> 2;            // row strip (rows wr*32..+31)
    int wc = w & 3;             // col group (cols wc*32..+31)
    int lr = l & 15, lkq = l >> 4;
    int lk = lkq * 8;
    int boff = (lr << 5) + (lkq << 3);
    int n0 = blockIdx.x * 64;

    if (tid < 64) SWs[tid] = (n0 + tid < N) ? sw[n0 + tid] : 0.f;

    // stage A [s|agg] 64 x 256 bf16, stride 264
    {
        int ar = tid >> 3;
        int kg = (tid & 7) * 8;
        int arow = n0 + ar; if (arow >= N) arow = N - 1;
        #pragma unroll
        for (int c = 0; c < 4; ++c) {
            int k = c * 64 + kg;
            BF8 pk;
            if (k < 128) {
                const float* asrc = s + (size_t)arow * 128 + k;
                float4 f0 = *(const float4*)asrc;
                float4 f1 = *(const float4*)(asrc + 4);
                pk.u[0] = f2bf(f0.x); pk.u[1] = f2bf(f0.y); pk.u[2] = f2bf(f0.z); pk.u[3] = f2bf(f0.w);
                pk.u[4] = f2bf(f1.x); pk.u[5] = f2bf(f1.y); pk.u[6] = f2bf(f1.z); pk.u[7] = f2bf(f1.w);
            } else {
                pk.v = *(const bf16x8*)(GAB + (size_t)arow * 128 + (k - 128));
            }
            *(bf16x8*)&Asub[ar * 264 + k] = pk.v;
        }
    }
    __syncthreads();

    // ---- Phase A: K=256, prefetched; wave cols = wc*32..+31 (g = wc*2+ct)
    f32x4 acc[2][2];
    #pragma unroll
    for (int i = 0; i < 2; ++i) { acc[i][0] = (f32x4){0,0,0,0}; acc[i][1] = (f32x4){0,0,0,0}; }

    int row0 = wr * 32 + lr;
    bf16x8 bcur[2], a0c, a1c;
    #pragma unroll
    for (int ct = 0; ct < 2; ++ct)
        bcur[ct] = *(const bf16x8*)(WUCF + (size_t)((wc * 2 + ct) * 8) * 512 + boff);
    a0c = *(const bf16x8*)&Asub[row0 * 264 + lk];
    a1c = *(const bf16x8*)&Asub[(row0 + 16) * 264 + lk];

    #pragma unroll
    for (int kk = 0; kk < 8; ++kk) {
        bf16x8 bn[2], a0n, a1n;
        if (kk < 7) {
            #pragma unroll
            for (int ct = 0; ct < 2; ++ct)
                bn[ct] = *(const bf16x8*)(WUCF + (size_t)((wc * 2 + ct) * 8 + kk + 1) * 512 + boff);
            a0n = *(const bf16x8*)&Asub[row0 * 264 + (kk + 1) * 32 + lk];
            a1n = *(const bf16x8*)&Asub[(row0 + 16) * 264 + (kk + 1) * 32 + lk];
        }
        #pragma unroll
        for (int ct = 0; ct < 2; ++ct) {
            acc[0][ct] = __builtin_amdgcn_mfma_f32_16x16x32_bf16(a0c, bcur[ct], acc[0][ct], 0, 0, 0);
            acc[1][ct] = __builtin_amdgcn_mfma_f32_16x16x32_bf16(a1c, bcur[ct], acc[1][ct], 0, 0, 0);
        }
        if (kk < 7) {
            bcur[0] = bn[0]; bcur[1] = bn[1];
            a0c = a0n; a1c = a1n;
        }
    }

    int rbase = lkq * 4;
    #pragma unroll
    for (int ct = 0; ct < 2; ++ct) {
        int col = wc * 32 + ct * 16 + lr;
        float b1 = bu1[col], bv = BV[col];
        #pragma unroll
        for (int rt = 0; rt < 2; ++rt) {
            #pragma unroll
            for (int r = 0; r < 4; ++r) {
                int row16 = wr * 32 + rt * 16 + rbase + r;
                float v = acc[rt][ct][r] + b1 + SWs[row16] * bv;
                H2[row16 * 136 + col] = (short)f2bf(gelu_fast(v));
            }
        }
    }
    __syncthreads();

    // ---- Phase B: K=128, prefetched
    f32x4 acc2[2][2];
    #pragma unroll
    for (int i = 0; i < 2; ++i) { acc2[i][0] = (f32x4){0,0,0,0}; acc2[i][1] = (f32x4){0,0,0,0}; }

    bf16x8 b2c[2], h0c, h1c;
    #pragma unroll
    for (int ct = 0; ct < 2; ++ct)
        b2c[ct] = *(const bf16x8*)(WU2F + (size_t)((wc * 2 + ct) * 4) * 512 + boff);
    h0c = *(const bf16x8*)&H2[row0 * 136 + lk];
    h1c = *(const bf16x8*)&H2[(row0 + 16) * 136 + lk];

    #pragma unroll
    for (int kk = 0; kk < 4; ++kk) {
        bf16x8 bn[2], h0n, h1n;
        if (kk < 3) {
            #pragma unroll
            for (int ct = 0; ct < 2; ++ct)
                bn[ct] = *(const bf16x8*)(WU2F + (size_t)((wc * 2 + ct) * 4 + kk + 1) * 512 + boff);
            h0n = *(const bf16x8*)&H2[row0 * 136 + (kk + 1) * 32 + lk];
            h1n = *(const bf16x8*)&H2[(row0 + 16) * 136 + (kk + 1) * 32 + lk];
        }
        #pragma unroll
        for (int ct = 0; ct < 2; ++ct) {
            acc2[0][ct] = __builtin_amdgcn_mfma_f32_16x16x32_bf16(h0c, b2c[ct], acc2[0][ct], 0, 0, 0);
            acc2[1][ct] = __builtin_amdgcn_mfma_f32_16x16x32_bf16(h1c, b2c[ct], acc2[1][ct], 0, 0, 0);
        }
        if (kk < 3) {
            b2c[0] = bn[0]; b2c[1] = bn[1];
            h0c = h0n; h1c = h1n;
        }
    }

    // ---- epilogue B: stage fp32 out-tile in LDS (64 x 132 floats, reuses
    // Asub — 33792B both ways), then fully-coalesced 16B stores.
    __syncthreads();                    // H2/Asub reads done
    float* Fout = (float*)Asub;
    #pragma unroll
    for (int ct = 0; ct < 2; ++ct) {
        int col = wc * 32 + ct * 16 + lr;
        float b2 = bu2[col];
        #pragma unroll
        for (int rt = 0; rt < 2; ++rt) {
            #pragma unroll
            for (int r = 0; r < 4; ++r) {
                int lrow = wr * 32 + rt * 16 + rbase + r;
                Fout[lrow * 132 + col] = acc2[rt][ct][r] + b2;
            }
        }
    }
    __syncthreads();
    {
        int lrow = tid >> 3;
        int arow = n0 + lrow;
        if (arow < N) {
            int c0 = tid & 7;
            #pragma unroll
            for (int cc = 0; cc < 4; ++cc) {
                int ch = c0 + cc * 8;            // 0..31 chunks of 4 floats
                float4 v = *(const float4*)&Fout[lrow * 132 + ch * 4];
                *(float4*)&out[(size_t)arow * 128 + ch * 4] = v;
            }
        }
    }
}

// ---------------------------------------------------------------------------
extern "C" void kernel_launch(void* const* d_in, const int* in_sizes, int n_in,
                              void* d_out, int out_size, void* d_ws, size_t ws_size,
                              hipStream_t stream) {
    const float* s    = (const float*)d_in[0];
    const float* x    = (const float*)d_in[1];
    const int*   ei   = (const int*)d_in[2];
    const float* ew   = (const float*)d_in[3];
    const float* t    = (const float*)d_in[4];
    const float* Wm1  = (const float*)d_in[5];
    const float* bm1  = (const float*)d_in[6];
    const float* Wm2  = (const float*)d_in[7];
    const float* bm2  = (const float*)d_in[8];
    const float* Wu1  = (const float*)d_in[9];
    const float* bu1  = (const float*)d_in[10];
    const float* Wu2  = (const float*)d_in[11];
    const float* bu2  = (const float*)d_in[12];

    int N = in_sizes[0] / 128;
    int E = in_sizes[2] / 2;
    const int* srcI = ei;
    const int* dstI = ei + E;
    int NP = (N + CHUNK - 1) & ~(CHUNK - 1);
    int C  = NP / CHUNK;

    // workspace layout (32-bit words)
    float* ws = (float*)d_ws;
    size_t off = 0;
    ushort* Pb   = (ushort*)(ws + off); off += (size_t)N * 64;
    ushort* Qb   = (ushort*)(ws + off); off += (size_t)N * 64;
    float*  SW   = ws + off; off += ((size_t)N + 63) & ~(size_t)63;
    ushort* GAB  = (ushort*)(ws + off); off += (size_t)N * 64;
    ushort* WC1F = (ushort*)(ws + off); off += (256 * 320) / 2;
    ushort* WUCF = (ushort*)(ws + off); off += (128 * 256) / 2;
    ushort* WU2F = (ushort*)(ws + off); off += (128 * 128) / 2;
    float*  BV   = ws + off; off += 128;
    int*    DEG  = (int*)(ws + off); off += (size_t)NP;
    int*    OFFS = (int*)(ws + off); off += (size_t)NP + 64;
    off = (off + 3) & ~(size_t)3;
    int*    RANK = (int*)(ws + off); off += (size_t)E;
    int*    CSUM = (int*)(ws + off); off += 128;
    int*    CBASE= (int*)(ws + off); off += 128;
    off = (off + 3) & ~(size_t)3;
    int2*   REC  = (int2*)(ws + off); off += (size_t)E * 2;

    // zero histogram, then fused weight-prep + histogram-with-rank
    hipMemsetAsync(DEG, 0, (size_t)NP * sizeof(int), stream);
    int histBlocks = (E + 255) / 256;
    k_prep<<<512 + histBlocks, 256, 0, stream>>>(Wm1, Wu1, Wm2, bm2, Wu2, dstI, E,
                                                 WC1F, WUCF, WU2F, BV, DEG, RANK);

    // counting sort tail (no atomics in scatter)
    k_chunksum<<<C, 256, 0, stream>>>(DEG, CSUM);
    k_chunkscan<<<1, 64, 0, stream>>>(CSUM, CBASE, C, OFFS, N, E);
    k_chunkoffs<<<C, 256, 0, stream>>>(DEG, CBASE, OFFS);
    k_scatter<<<(E + 255) / 256, 256, 0, stream>>>(srcI, dstI, ew, OFFS, RANK, REC, E);

    // node precompute (MFMA, coalesced epilogue)
    int nb64 = (N + 63) / 64;
    k1_mfma<<<nb64, 512, 0, stream>>>(s, x, t, WC1F, bm1, Pb, Qb, N);

    // segmented aggregation (tanh gelu, 8-deep pipelined gathers)
    k_agg<<<(N + 3) / 4, 256, 0, stream>>>(Pb, Qb, REC, OFFS, GAB, SW, N);

    // update MLP (MFMA, 64-row blocks, coalesced fp32 epilogue)
    k3_mfma<<<nb64, 512, 0, stream>>>(s, GAB, SW, WUCF, BV, bu1, WU2F, bu2, (float*)d_out, N);
}